// Round 9
// baseline (789.031 us; speedup 1.0000x reference)
//
#include <hip/hip_runtime.h>
#include <math.h>
#include <stddef.h>

// TransformNet fused pipeline, fp32.
// B=8, C=6, N=4096, K=20.
//
// ws layout (bytes):
//   [0)          xtp   : 8*4096*8 floats (points padded to 8)    1,048,576
//                        (REUSED after k_conv12 as w3t: 128x1024 = 524,288)
//   [1048576)    idx   : 8*4096*20 ints                          2,621,440
//   [3670016)    h2max : 8*4096*128 floats                      16,777,216
//   [20447232)   zstats: zero-initialized stats block                42,496
//   [20489728)   tail  : bn1st(128) bn2st(256) g(8192) h4(4096) g4(4096)
//                        h5(2048) g5(2048) mat(72) bias3(24)        83,840
//   [20573568)   w2t_g : 64x128 floats (w2 transposed)              32,768

static constexpr float EPS_ = 1e-5f;

// ---------------- K1: transpose-pad points + squared norms (+ w2 transpose) ----------------
__global__ __launch_bounds__(256) void k_prep(const float* __restrict__ x,
                                              float* __restrict__ xtp,
                                              const float* __restrict__ w2,
                                              float* __restrict__ w2t)
{
    int i = blockIdx.x*256 + threadIdx.x;       // 0..32767  (b*4096+n)
    int b = i >> 12, n = i & 4095;
    const float* xb = x + (size_t)b*6*4096 + n;
    float v0 = xb[0], v1 = xb[4096], v2 = xb[2*4096];
    float v3 = xb[3*4096], v4 = xb[4*4096], v5 = xb[5*4096];
    float xx = v0*v0 + v1*v1 + v2*v2 + v3*v3 + v4*v4 + v5*v5;
    float4* o = (float4*)(xtp + (size_t)i*8);
    o[0] = make_float4(v0, v1, v2, v3);
    o[1] = make_float4(v4, v5, xx, 0.f);
    if (blockIdx.x < 2){                        // w2t[c][o] = w2[o][c]
        int e = blockIdx.x*256 + threadIdx.x;   // 0..511
        for (int q = e; q < 64*128; q += 512){
            int c = q >> 7, oo = q & 127;
            w2t[q] = w2[oo*64 + c];
        }
    }
}

// identical fmaf chain used in both the max pass and the recompute pass so
// values are bit-identical.
__device__ __forceinline__ float pd_calc(const float4 a0, const float4 a1,
                                         const float4 q0, const float4 q1)
{
    float dot = a0.x*q0.x;
    dot = fmaf(a0.y, q0.y, dot);
    dot = fmaf(a0.z, q0.z, dot);
    dot = fmaf(a0.w, q0.w, dot);
    dot = fmaf(a1.x, q1.x, dot);
    dot = fmaf(a1.y, q1.y, dot);
    return fmaf(2.f, dot, -a1.z - q1.z);
}

// monotone float<->uint key transform (order-preserving, exact)
__device__ __forceinline__ unsigned fkey_(float f){
    unsigned u = __float_as_uint(f);
    return (u & 0x80000000u) ? ~u : (u | 0x80000000u);
}
__device__ __forceinline__ float finv_(unsigned k){
    return (k & 0x80000000u) ? __uint_as_float(k & 0x7fffffffu)
                             : __uint_as_float(~k);
}

// ---------------- K2: top-20 (as a SET; downstream is order-invariant) ----------------
#define TK_CAP 384
__global__ __launch_bounds__(256) void k_topk(const float* __restrict__ xtp,
                                              int* __restrict__ idxout)
{
    __shared__ float maxs[4][256];
    __shared__ float candv[4][TK_CAP];
    __shared__ int   candi[4][TK_CAP];
    __shared__ float Ts[4];
    __shared__ unsigned ccnt[4], ocnt[4], nwork;
    __shared__ unsigned short work[1024];

    const int t = threadIdx.x;
    const int rowbase = blockIdx.x << 2;        // 4 centers per block
    const int b = rowbase >> 12;
    const float* xb = xtp + ((size_t)b << 15);  // b*4096*8

    float4 c0[4], c1[4];
    #pragma unroll
    for (int c = 0; c < 4; c++){
        const float4* p = (const float4*)(xtp + (size_t)(rowbase + c)*8);
        c0[c] = p[0]; c1[c] = p[1];
    }
    if (t < 4){ ccnt[t] = 0u; ocnt[t] = 0u; }
    if (t == 0) nwork = 0u;

    // phase 1: per-thread max over its 16 points, all 4 centers
    float mx[4] = {-INFINITY, -INFINITY, -INFINITY, -INFINITY};
    {
        const float4* qp = (const float4*)(xb + (size_t)t*8);
        for (int i = 0; i < 16; i++){
            float4 q0 = qp[0], q1 = qp[1];
            #pragma unroll
            for (int c = 0; c < 4; c++)
                mx[c] = fmaxf(mx[c], pd_calc(c0[c], c1[c], q0, q1));
            qp += 512;                          // +256 points
        }
    }
    #pragma unroll
    for (int c = 0; c < 4; c++) maxs[c][t] = mx[c];
    __syncthreads();

    const int w = t >> 6, lane = t & 63;
    {   // phase 2: exact 20th-largest of maxima via ballot binary search
        unsigned k0 = fkey_(maxs[w][lane]);
        unsigned k1 = fkey_(maxs[w][64  + lane]);
        unsigned k2 = fkey_(maxs[w][128 + lane]);
        unsigned k3 = fkey_(maxs[w][192 + lane]);
        unsigned lo = 0u;
        for (int bit = 31; bit >= 0; bit--){
            unsigned cand = lo | (1u << bit);
            int cnt = __popcll(__ballot(k0 >= cand))
                    + __popcll(__ballot(k1 >= cand))
                    + __popcll(__ballot(k2 >= cand))
                    + __popcll(__ballot(k3 >= cand));
            if (cnt >= 20) lo = cand;
        }
        if (lane == 0) Ts[w] = finv_(lo);
    }
    __syncthreads();

    // phase 3a: compact worklist of qualifying (center, src-thread)
    #pragma unroll
    for (int c = 0; c < 4; c++){
        if (mx[c] >= Ts[c]){
            unsigned pos = atomicAdd(&nwork, 1u);
            work[pos] = (unsigned short)((c << 8) | t);
        }
    }
    __syncthreads();

    // phase 3b: dense recompute; push candidates >= threshold
    {
        int total = (int)nwork << 4;
        for (int e = t; e < total; e += 256){
            int ct = work[e >> 4];
            int c = ct >> 8, src = ct & 255;
            int m = ((e & 15) << 8) | src;
            const float4* p = (const float4*)(xb + (size_t)m*8);
            float4 q0 = p[0], q1 = p[1];
            float pd = pd_calc(c0[c], c1[c], q0, q1);
            if (pd >= Ts[c]){
                unsigned pos = atomicAdd(&ccnt[c], 1u);
                if (pos < TK_CAP){ candv[c][pos] = pd; candi[c][pos] = m; }
            }
        }
    }
    __syncthreads();

    {   // phase 4: exact top-20 set of center w's candidates
        int n = (int)min(ccnt[w], (unsigned)TK_CAP);
        unsigned key[6]; int id[6];
        #pragma unroll
        for (int j = 0; j < 6; j++){
            int p = (j << 6) | lane;
            bool ok = p < n;
            key[j] = ok ? fkey_(candv[w][p]) : 0u;     // 0 < any finite key
            id[j]  = ok ? candi[w][p] : 0x7fffffff;
        }
        unsigned C = 0u;                               // cutoff key (20th largest)
        for (int bit = 31; bit >= 0; bit--){
            unsigned cand = C | (1u << bit);
            int cnt = 0;
            #pragma unroll
            for (int j = 0; j < 6; j++)
                cnt += __popcll(__ballot(key[j] >= cand));
            if (cnt >= 20) C = cand;
        }
        int m = 0, e = 0;
        #pragma unroll
        for (int j = 0; j < 6; j++){
            m += __popcll(__ballot(key[j] > C));
            e += __popcll(__ballot(key[j] == C));
        }
        int* outp = idxout + (size_t)(rowbase + w)*20;
        #pragma unroll
        for (int j = 0; j < 6; j++){
            if (key[j] > C){
                unsigned pos = atomicAdd(&ocnt[w], 1u);
                outp[pos] = id[j];
            }
        }
        int need = 20 - m;                             // >= 1; e >= need always
        if (e <= need){                                // no boundary tie surplus
            #pragma unroll
            for (int j = 0; j < 6; j++){
                if (key[j] == C){
                    unsigned pos = atomicAdd(&ocnt[w], 1u);
                    outp[pos] = id[j];
                }
            }
        } else {                                       // rare: ties at cutoff
            for (int r = 0; r < need; r++){
                int loc = 0x7fffffff;
                #pragma unroll
                for (int j = 0; j < 6; j++)
                    if (key[j] == C && id[j] < loc) loc = id[j];
                int g = loc;
                #pragma unroll
                for (int s = 1; s < 64; s <<= 1) g = min(g, __shfl_xor(g, s));
                #pragma unroll
                for (int j = 0; j < 6; j++){
                    if (key[j] == C && id[j] == g){
                        key[j] = 0u;                   // remove; emit once
                        unsigned pos = atomicAdd(&ocnt[w], 1u);
                        outp[pos] = g;
                    }
                }
            }
        }
    }
}

// ---------------- K3: bn1 stats ----------------
__global__ __launch_bounds__(256) void k_bn1stats(const float* __restrict__ xtp,
                                                  const int* __restrict__ idxb,
                                                  const float* __restrict__ w1,
                                                  float* __restrict__ bn1sum,
                                                  float* __restrict__ bn1sq)
{
    __shared__ float fT[320*12];                // 16 rows * 20 nbrs * 12
    __shared__ float red[2][4][64];
    const int t = threadIdx.x;
    const int rowbase = blockIdx.x << 4;        // 16 rows
    const int b = rowbase >> 12;

    for (int s = t; s < 320; s += 256){
        int r = s / 20, k = s % 20;
        int grow = rowbase + r;
        int m = idxb[(size_t)grow*20 + k];
        const float4* pn = (const float4*)(xtp + (size_t)((b << 12) | m)*8);
        const float4* pc = (const float4*)(xtp + (size_t)grow*8);
        float4 n0 = pn[0], n1 = pn[1], c0 = pc[0], c1 = pc[1];
        float* f = fT + s*12;
        ((float4*)f)[0] = make_float4(n0.x-c0.x, n0.y-c0.y, n0.z-c0.z, n0.w-c0.w);
        ((float4*)f)[1] = make_float4(n1.x-c1.x, n1.y-c1.y, c0.x, c0.y);
        ((float4*)f)[2] = make_float4(c0.z, c0.w, c1.x, c1.y);
    }
    __syncthreads();
    const int o = t & 63, grp = t >> 6;
    float w[12];
    #pragma unroll
    for (int c = 0; c < 12; c++) w[c] = w1[o*12 + c];
    float sm = 0.f, sq = 0.f;
    for (int s = grp*80; s < grp*80 + 80; s++){
        const float* f = fT + s*12;
        float4 f0 = *(const float4*)(f);
        float4 fa = *(const float4*)(f + 4);
        float4 fb = *(const float4*)(f + 8);
        float h = w[0]*f0.x + w[1]*f0.y + w[2]*f0.z + w[3]*f0.w
                + w[4]*fa.x + w[5]*fa.y + w[6]*fa.z + w[7]*fa.w
                + w[8]*fb.x + w[9]*fb.y + w[10]*fb.z + w[11]*fb.w;
        sm += h; sq = fmaf(h, h, sq);
    }
    red[0][grp][o] = sm; red[1][grp][o] = sq;
    __syncthreads();
    if (t < 64){
        float a = red[0][0][t] + red[0][1][t] + red[0][2][t] + red[0][3][t];
        float c2 = red[1][0][t] + red[1][1][t] + red[1][2][t] + red[1][3][t];
        atomicAdd(bn1sum + t, a);
        atomicAdd(bn1sq + t, c2);
    }
}

// ---------------- generic BN finalize ----------------
__global__ void k_bnfin(const float* __restrict__ sum, const float* __restrict__ sq,
                        const float* __restrict__ gamma, const float* __restrict__ beta,
                        float* __restrict__ st, int C, float invN)
{
    int o = threadIdx.x;
    if (o < C){
        float mean = sum[o]*invN;
        float var  = sq[o]*invN - mean*mean;
        float s = gamma[o]/sqrtf(var + EPS_);
        st[o] = s;
        st[C + o] = beta[o] - mean*s;
    }
}

// ---------------- K4: fused conv1+bn1+lrelu+conv2 -> max_k + bn2 stats ----------------
// conv2 register tile 5 vec x 8 o. f1s XOR-swizzled (2-way max). w2 panels at
// 516-word stride, staged via linear global read (R7 scheme, write 2-way free).
// Epilogue scratch: slot = og*140 + vg*8 + (vg>>2)*4 — 16-lane write group hits
// all 8 bank-quads exactly twice (= HW minimum, conflict-free); reads 2-way.
__global__ __launch_bounds__(256, 3) void k_conv12(
    const float* __restrict__ xtp, const int* __restrict__ idxb,
    const float* __restrict__ w1, const float* __restrict__ w2t,
    const float* __restrict__ bn1st,
    float* __restrict__ h2max, float* __restrict__ bn2sum, float* __restrict__ bn2sq)
{
    __shared__ float f1s[80*64];        // 20480 B  conv1 out, XOR-swizzled j
    __shared__ float w2u[16*516];       // 33024 B  w2 panels; fT alias; scratch alias
    const int t = threadIdx.x;
    const int rowbase = blockIdx.x << 2;
    const int b = rowbase >> 12;

    // w1 row into regs (j = t&63 owns output channel j)
    const int jch = t & 63;
    float wr[12];
    #pragma unroll
    for (int c = 0; c < 12; c++) wr[c] = w1[jch*12 + c];

    float* fT = w2u;                    // fT[80][12] aliases first 960 floats of w2u
    if (t < 80){
        int r = t / 20;
        int grow = rowbase + r;
        int m = idxb[(size_t)grow*20 + (t - r*20)];
        const float4* pn = (const float4*)(xtp + (size_t)((b << 12) | m)*8);
        const float4* pc = (const float4*)(xtp + (size_t)grow*8);
        float4 n0 = pn[0], n1 = pn[1], c0 = pc[0], c1 = pc[1];
        float* f = fT + t*12;
        ((float4*)f)[0] = make_float4(n0.x-c0.x, n0.y-c0.y, n0.z-c0.z, n0.w-c0.w);
        ((float4*)f)[1] = make_float4(n1.x-c1.x, n1.y-c1.y, c0.x, c0.y);
        ((float4*)f)[2] = make_float4(c0.z, c0.w, c1.x, c1.y);
    }
    __syncthreads();                    // sync1: fT ready
    {   // conv1 + bn1 + lrelu -> f1s (XOR-swizzled j within each vec row)
        const float s1 = bn1st[jch], t1 = bn1st[64 + jch];
        for (int vid = t; vid < 5120; vid += 256){
            int vec = vid >> 6;
            const float* f = fT + vec*12;
            float4 f0 = *(const float4*)(f);
            float4 fa = *(const float4*)(f + 4);
            float4 fb = *(const float4*)(f + 8);
            float acc = wr[0]*f0.x + wr[1]*f0.y + wr[2]*f0.z + wr[3]*f0.w
                      + wr[4]*fa.x + wr[5]*fa.y + wr[6]*fa.z + wr[7]*fa.w
                      + wr[8]*fb.x + wr[9]*fb.y + wr[10]*fb.z + wr[11]*fb.w;
            float v = fmaf(s1, acc, t1);
            f1s[(vec << 6) + (jch ^ ((vec & 7) << 2))] = fmaxf(v, 0.2f*v);
        }
    }
    __syncthreads();                    // sync2: f1s ready, fT dead
    {   // short-liveness copy w2t -> w2u panels (linear coalesced global read;
        // panel write is 2-way = free, measured R7)
        float4 tmp[8];
        #pragma unroll
        for (int i = 0; i < 8; i++) tmp[i] = ((const float4*)w2t)[t + (i << 8)];
        #pragma unroll
        for (int i = 0; i < 8; i++){
            int q = t + (i << 8);               // float4 id
            int jr = q >> 5, o4 = q & 31;
            *(float4*)&w2u[(o4 >> 1)*516 + (jr << 3) + ((o4 & 1) << 2)] = tmp[i];
        }
    }
    __syncthreads();                    // sync3: w2u ready

    // conv2: thread = (vg owns 5 vecs of row r=vg>>2, og owns 8 o's)
    const int vg = t & 15, og = t >> 4;
    const float* fp = f1s + vg*5*64;
    const float* wp = w2u + og*516;
    int xw[5];
    #pragma unroll
    for (int i = 0; i < 5; i++) xw[i] = ((vg*5 + i) & 7) << 2;

    float h[5][8];
    #pragma unroll
    for (int i = 0; i < 5; i++)
        #pragma unroll
        for (int oi = 0; oi < 8; oi++) h[i][oi] = 0.f;

    #pragma unroll
    for (int jl = 0; jl < 64; jl += 4){
        float wv[4][8];
        #pragma unroll
        for (int jj = 0; jj < 4; jj++){
            *(float4*)&wv[jj][0] = *(const float4*)&wp[((jl + jj) << 3)];
            *(float4*)&wv[jj][4] = *(const float4*)&wp[((jl + jj) << 3) + 4];
        }
        #pragma unroll
        for (int i = 0; i < 5; i++){
            float fv[4];
            *(float4*)fv = *(const float4*)&fp[(i << 6) + (jl ^ xw[i])];
            #pragma unroll
            for (int jj = 0; jj < 4; jj++)
                #pragma unroll
                for (int oi = 0; oi < 8; oi++)
                    h[i][oi] = fmaf(fv[jj], wv[jj][oi], h[i][oi]);
        }
    }

    // fold the 5 k's in-register
    float mxl[8], sml[8], sql[8];
    #pragma unroll
    for (int oi = 0; oi < 8; oi++){
        float v = h[0][oi];
        mxl[oi] = v; sml[oi] = v; sql[oi] = v*v;
    }
    #pragma unroll
    for (int i = 1; i < 5; i++)
        #pragma unroll
        for (int oi = 0; oi < 8; oi++){
            float v = h[i][oi];
            mxl[oi] = fmaxf(mxl[oi], v);
            sml[oi] += v;
            sql[oi] = fmaf(v, v, sql[oi]);
        }
    __syncthreads();                    // sync4: f1s+w2u reusable
    {   // bank-skewed per-thread slot: 16-lane group covers 8 quads x2 (free)
        const int slot = og*140 + (vg << 3) + ((vg >> 2) << 2);
        *(float4*)&w2u[slot]     = *(float4*)&mxl[0];
        *(float4*)&w2u[slot + 4] = *(float4*)&mxl[4];
        *(float4*)&w2u[2240 + slot]     = *(float4*)&sml[0];
        *(float4*)&w2u[2240 + slot + 4] = *(float4*)&sml[4];
        *(float4*)&w2u[4480 + slot]     = *(float4*)&sql[0];
        *(float4*)&w2u[4480 + slot + 4] = *(float4*)&sql[4];
    }
    __syncthreads();                    // sync5
    for (int it = t; it < 512; it += 256){
        int r = it >> 7, o = it & 127;
        int og2 = o >> 3, c = o & 7;
        // slot(vg=4r+q, og2) = og2*140 + r*36 + q*8 + c
        int base = og2*140 + r*36 + c;
        float m = w2u[base];
        #pragma unroll
        for (int q = 1; q < 4; q++) m = fmaxf(m, w2u[base + (q << 3)]);
        h2max[(size_t)(rowbase + r)*128 + o] = m;
    }
    if (t < 128){
        int og2 = t >> 3, c = t & 7;
        float s = 0.f, qq = 0.f;
        #pragma unroll
        for (int u = 0; u < 16; u++){
            int off = og2*140 + (u << 3) + ((u >> 2) << 2) + c;
            s  += w2u[2240 + off];
            qq += w2u[4480 + off];
        }
        atomicAdd(bn2sum + t, s);
        atomicAdd(bn2sq + t, qq);
    }
}

// ---------------- w3 transpose into dead xtp region ----------------
__global__ __launch_bounds__(256) void k_wt3(const float* __restrict__ w3,
                                             float* __restrict__ w3t)
{
    int i = blockIdx.x*256 + threadIdx.x;       // 0..131071
    int j = i >> 10, o = i & 1023;
    w3t[i] = w3[(size_t)o*128 + j];             // w3t[j][o]
}

// ---------------- K5: bn2+lrelu+conv3 -> bn3 stats + max over n ----------------
// w3 panel copied into LDS with short register liveness (no spill); XCD-contiguous
// block remap for h2max L2 reuse; 48.5KB LDS -> 3 blocks/CU; 3 barriers.
__global__ __launch_bounds__(256, 3) void k_conv3(const float* __restrict__ h2max,
    const float* __restrict__ bn2st, const float* __restrict__ w3t,
    float* __restrict__ bn3sum, float* __restrict__ bn3sq, unsigned int* __restrict__ gkey)
{
    __shared__ float f2[32*132];        // 16.5 KB (pad 132 keeps GEMM broadcast rows on distinct banks)
    __shared__ float w3s[8192];         // 32.0 KB  [j=128][o=64] linear
    const int t = threadIdx.x;
    // XCD-contiguous remap: blocks sharing an h2max tile land on one XCD's L2
    const int bid = blockIdx.x;
    const int idx = bid >> 3;
    const int rt = (bid & 7)*128 + (idx >> 4);  // 1024 row tiles of 32
    const int ot = idx & 15;                    // 16 o-tiles of 64
    const int rowbase = rt << 5;
    const int obase = ot << 6;
    const int b = rowbase >> 12;

    for (int e = t; e < 32*128; e += 256){
        int r = e >> 7, c = e & 127;
        float v = h2max[(size_t)(rowbase + r)*128 + c];
        float u = fmaf(bn2st[c], v, bn2st[128 + c]);
        f2[r*132 + c] = fmaxf(u, 0.2f*u);
    }
    {   // short-liveness copy of w3 panel -> w3s
        float4 tmp[8];
        #pragma unroll
        for (int i = 0; i < 8; i++){
            int q = t + (i << 8);               // 0..2047
            tmp[i] = *(const float4*)&w3t[(size_t)(q >> 4)*1024 + obase + ((q & 15) << 2)];
        }
        #pragma unroll
        for (int i = 0; i < 8; i++) ((float4*)w3s)[t + (i << 8)] = tmp[i];
    }
    __syncthreads();                    // sync1: f2 + w3s ready

    const int oq = t & 15, rg = t >> 4;
    const int o0 = oq << 2, r0 = rg << 1;
    float h0[4] = {0.f,0.f,0.f,0.f}, h1[4] = {0.f,0.f,0.f,0.f};
    for (int jl = 0; jl < 128; jl += 4){
        float wv[4][4];
        #pragma unroll
        for (int jj = 0; jj < 4; jj++)
            *(float4*)wv[jj] = *(const float4*)&w3s[(jl + jj)*64 + o0];
        float fa[4], fb[4];
        *(float4*)fa = *(const float4*)&f2[r0*132 + jl];
        *(float4*)fb = *(const float4*)&f2[(r0 + 1)*132 + jl];
        #pragma unroll
        for (int jj = 0; jj < 4; jj++)
            #pragma unroll
            for (int oi = 0; oi < 4; oi++){
                h0[oi] = fmaf(fa[jj], wv[jj][oi], h0[oi]);
                h1[oi] = fmaf(fb[jj], wv[jj][oi], h1[oi]);
            }
    }
    __syncthreads();                    // sync2: f2 reusable as scratch
    float* scr = f2;                    // [3][16 rg][64 o]
    *(float4*)&scr[(rg << 6) + o0] =
        make_float4(h0[0]+h1[0], h0[1]+h1[1], h0[2]+h1[2], h0[3]+h1[3]);
    *(float4*)&scr[1024 + (rg << 6) + o0] =
        make_float4(h0[0]*h0[0]+h1[0]*h1[0], h0[1]*h0[1]+h1[1]*h1[1],
                    h0[2]*h0[2]+h1[2]*h1[2], h0[3]*h0[3]+h1[3]*h1[3]);
    *(float4*)&scr[2048 + (rg << 6) + o0] =
        make_float4(fmaxf(h0[0],h1[0]), fmaxf(h0[1],h1[1]),
                    fmaxf(h0[2],h1[2]), fmaxf(h0[3],h1[3]));
    __syncthreads();                    // sync3
    if (t < 192){
        int stat = t >> 6, o = t & 63;
        if (stat == 0){
            float s = 0.f;
            #pragma unroll
            for (int g2 = 0; g2 < 16; g2++) s += scr[(g2 << 6) + o];
            atomicAdd(bn3sum + obase + o, s);
        } else if (stat == 1){
            float s = 0.f;
            #pragma unroll
            for (int g2 = 0; g2 < 16; g2++) s += scr[1024 + (g2 << 6) + o];
            atomicAdd(bn3sq + obase + o, s);
        } else {
            float m = scr[2048 + o];
            #pragma unroll
            for (int g2 = 1; g2 < 16; g2++) m = fmaxf(m, scr[2048 + (g2 << 6) + o]);
            unsigned u = __float_as_uint(m);
            unsigned key = (u & 0x80000000u) ? ~u : (u | 0x80000000u);
            atomicMax(gkey + (b << 10) + obase + o, key);
        }
    }
}

// ---------------- K5f: finalize bn3 + g = lrelu(bn3(gmax)) ----------------
__global__ void k_bn3g(const float* __restrict__ sum, const float* __restrict__ sq,
                       const unsigned int* __restrict__ gkey,
                       const float* __restrict__ gamma, const float* __restrict__ beta,
                       float* __restrict__ g)
{
    int o = blockIdx.x*256 + threadIdx.x;
    if (o < 1024){
        float mean = sum[o]*(1.f/32768.f);
        float var  = sq[o]*(1.f/32768.f) - mean*mean;
        float s = gamma[o]/sqrtf(var + EPS_);
        float tt = beta[o] - mean*s;
        for (int b = 0; b < 8; b++){
            unsigned k = gkey[(b << 10) + o];
            unsigned u = (k & 0x80000000u) ? (k & 0x7fffffffu) : ~k;
            float v = __uint_as_float(u);
            float xv = fmaf(s, v, tt);
            g[(b << 10) + o] = fmaxf(xv, 0.2f*xv);
        }
    }
}

// ---------------- FC: one wave per output ----------------
__global__ __launch_bounds__(256) void k_fc(const float* __restrict__ in,
                                            const float* __restrict__ w,
                                            float* __restrict__ out, int Kdim, int Odim)
{
    int wid = (blockIdx.x*256 + threadIdx.x) >> 6;
    int lane = threadIdx.x & 63;
    int nout = 8*Odim;
    if (wid >= nout) return;
    int b = wid / Odim, o = wid - b*Odim;
    const float* gi = in + (size_t)b*Kdim;
    const float* wr = w + (size_t)o*Kdim;
    float acc = 0.f;
    for (int c = lane; c < Kdim; c += 64) acc = fmaf(gi[c], wr[c], acc);
    #pragma unroll
    for (int s = 32; s > 0; s >>= 1) acc += __shfl_xor(acc, s);
    if (lane == 0) out[(size_t)b*Odim + o] = acc;
}

// ---------------- batch-BN (over B=8) + lrelu ----------------
__global__ void k_bnb(const float* __restrict__ h, const float* __restrict__ gamma,
                      const float* __restrict__ beta, float* __restrict__ g, int C)
{
    int o = blockIdx.x*256 + threadIdx.x;
    if (o < C){
        float s = 0.f, q = 0.f;
        for (int b = 0; b < 8; b++){ float v = h[(size_t)b*C + o]; s += v; q = fmaf(v, v, q); }
        float mean = s*0.125f;
        float var  = q*0.125f - mean*mean;
        float sc = gamma[o]/sqrtf(var + EPS_);
        float tt = beta[o] - mean*sc;
        for (int b = 0; b < 8; b++){
            float xv = fmaf(sc, h[(size_t)b*C + o], tt);
            g[(size_t)b*C + o] = fmaxf(xv, 0.2f*xv);
        }
    }
}

// ---------------- head: fc3 (-> I + 3x3) and fc4 (-> bias) ----------------
__global__ void k_head(const float* __restrict__ g5,
                       const float* __restrict__ fc3w, const float* __restrict__ fc3b,
                       const float* __restrict__ fc4w, const float* __restrict__ fc4b,
                       float* __restrict__ mat, float* __restrict__ bias3)
{
    int t = threadIdx.x;
    if (t < 96){
        int b = t / 12, j = t % 12;
        const float* gi = g5 + b*256;
        if (j < 9){
            const float* w = fc3w + j*256;
            float a = fc3b[j];
            for (int c = 0; c < 256; c++) a = fmaf(gi[c], w[c], a);
            if (j == 0 || j == 4 || j == 8) a += 1.f;
            mat[b*9 + j] = a;
        } else {
            int d = j - 9;
            const float* w = fc4w + d*256;
            float a = fc4b[d];
            for (int c = 0; c < 256; c++) a = fmaf(gi[c], w[c], a);
            bias3[b*3 + d] = a;
        }
    }
}

// ---------------- final transform: out[b,d,n] ----------------
__global__ __launch_bounds__(256) void k_out(const float* __restrict__ x,
                                             const float* __restrict__ mat,
                                             const float* __restrict__ bias3,
                                             float* __restrict__ out)
{
    int i = blockIdx.x*256 + threadIdx.x;       // 0..98303
    int n = i & 4095, bd = i >> 12;
    int b = bd / 3, d = bd - b*3;
    const float* xb = x + (size_t)b*6*4096 + n;
    const float* M = mat + b*9;
    out[i] = xb[0]*M[d] + xb[4096]*M[3 + d] + xb[2*4096]*M[6 + d] + bias3[b*3 + d];
}

// ---------------- launch ----------------
extern "C" void kernel_launch(void* const* d_in, const int* in_sizes, int n_in,
                              void* d_out, int out_size, void* d_ws, size_t ws_size,
                              hipStream_t stream)
{
    const float* x     = (const float*)d_in[0];
    const float* w1    = (const float*)d_in[1];
    const float* bn1g  = (const float*)d_in[2];
    const float* bn1b  = (const float*)d_in[3];
    const float* w2    = (const float*)d_in[4];
    const float* bn2g  = (const float*)d_in[5];
    const float* bn2b  = (const float*)d_in[6];
    const float* w3    = (const float*)d_in[7];
    const float* bn3gm = (const float*)d_in[8];
    const float* bn3bt = (const float*)d_in[9];
    const float* fc1w  = (const float*)d_in[10];
    const float* bn4g  = (const float*)d_in[11];
    const float* bn4b  = (const float*)d_in[12];
    const float* fc2w  = (const float*)d_in[13];
    const float* bn5g  = (const float*)d_in[14];
    const float* bn5b  = (const float*)d_in[15];
    const float* fc3w  = (const float*)d_in[16];
    const float* fc3b  = (const float*)d_in[17];
    const float* fc4w  = (const float*)d_in[18];
    const float* fc4b  = (const float*)d_in[19];
    float* out = (float*)d_out;

    char* ws = (char*)d_ws;
    float* xtp   = (float*)(ws);
    float* w3t_g = (float*)(ws);                 // overwrites xtp AFTER k_conv12
    int*   idxb  = (int*)  (ws + 1048576);
    float* h2max = (float*)(ws + 3670016);
    float* zs    = (float*)(ws + 20447232);
    float* bn1sum = zs;            float* bn1sq = zs + 64;
    float* bn2sum = zs + 128;      float* bn2sq = zs + 256;
    float* bn3sum = zs + 384;      float* bn3sq = zs + 1408;
    unsigned int* gkey = (unsigned int*)(zs + 2432);
    float* tail  = (float*)(ws + 20489728);
    float* bn1st = tail;           // 128
    float* bn2st = tail + 128;     // 256
    float* g     = tail + 384;     // 8192
    float* h4    = tail + 8576;    // 4096
    float* g4    = tail + 12672;   // 4096
    float* h5    = tail + 16768;   // 2048
    float* g5    = tail + 18816;   // 2048
    float* mat   = tail + 20864;   // 72
    float* bias3 = tail + 20936;   // 24
    float* w2t_g = (float*)(ws + 20573568);      // 32KB

    hipMemsetAsync(zs, 0, 42496, stream);

    k_prep    <<<128,   256, 0, stream>>>(x, xtp, w2, w2t_g);
    k_topk    <<<8192,  256, 0, stream>>>(xtp, idxb);
    k_bn1stats<<<2048,  256, 0, stream>>>(xtp, idxb, w1, bn1sum, bn1sq);
    k_bnfin   <<<1,     128, 0, stream>>>(bn1sum, bn1sq, bn1g, bn1b, bn1st, 64, 1.f/655360.f);
    k_conv12  <<<8192,  256, 0, stream>>>(xtp, idxb, w1, w2t_g, bn1st, h2max, bn2sum, bn2sq);
    k_wt3     <<<512,   256, 0, stream>>>(w3, w3t_g);
    k_bnfin   <<<1,     128, 0, stream>>>(bn2sum, bn2sq, bn2g, bn2b, bn2st, 128, 1.f/655360.f);
    k_conv3   <<<16384, 256, 0, stream>>>(h2max, bn2st, w3t_g, bn3sum, bn3sq, gkey);
    k_bn3g    <<<4,     256, 0, stream>>>(bn3sum, bn3sq, gkey, bn3gm, bn3bt, g);
    k_fc      <<<1024,  256, 0, stream>>>(g, fc1w, h4, 1024, 512);
    k_bnb     <<<2,     256, 0, stream>>>(h4, bn4g, bn4b, g4, 512);
    k_fc      <<<512,   256, 0, stream>>>(g4, fc2w, h5, 512, 256);
    k_bnb     <<<1,     256, 0, stream>>>(h5, bn5g, bn5b, g5, 256);
    k_head    <<<1,     128, 0, stream>>>(g5, fc3w, fc3b, fc4w, fc4b, mat, bias3);
    k_out     <<<384,   256, 0, stream>>>(x, mat, bias3, out);
}

// Round 10
// 757.011 us; speedup vs baseline: 1.0423x; 1.0423x over previous
//
#include <hip/hip_runtime.h>
#include <math.h>
#include <stddef.h>

// TransformNet fused pipeline, fp32.
// B=8, C=6, N=4096, K=20.
//
// ws layout (bytes):
//   [0)          xtp   : 8*4096*8 floats (points padded to 8)    1,048,576
//                        (REUSED after k_conv12 as w3t: 128x1024 = 524,288)
//   [1048576)    idx   : 8*4096*20 ints                          2,621,440
//   [3670016)    h2max : 8*4096*128 floats                      16,777,216
//   [20447232)   zstats: zero-initialized stats block                42,496
//   [20489728)   tail  : bn1st(128) bn2st(256) g(8192) h4(4096) g4(4096)
//                        h5(2048) g5(2048) mat(72) bias3(24)        83,840
//   [20573568)   w2t_g : 64x128 floats (w2 transposed)              32,768

static constexpr float EPS_ = 1e-5f;

// ---------------- K1: transpose-pad points + squared norms (+ w2 transpose) ----------------
__global__ __launch_bounds__(256) void k_prep(const float* __restrict__ x,
                                              float* __restrict__ xtp,
                                              const float* __restrict__ w2,
                                              float* __restrict__ w2t)
{
    int i = blockIdx.x*256 + threadIdx.x;       // 0..32767  (b*4096+n)
    int b = i >> 12, n = i & 4095;
    const float* xb = x + (size_t)b*6*4096 + n;
    float v0 = xb[0], v1 = xb[4096], v2 = xb[2*4096];
    float v3 = xb[3*4096], v4 = xb[4*4096], v5 = xb[5*4096];
    float xx = v0*v0 + v1*v1 + v2*v2 + v3*v3 + v4*v4 + v5*v5;
    float4* o = (float4*)(xtp + (size_t)i*8);
    o[0] = make_float4(v0, v1, v2, v3);
    o[1] = make_float4(v4, v5, xx, 0.f);
    if (blockIdx.x < 2){                        // w2t[c][o] = w2[o][c]
        int e = blockIdx.x*256 + threadIdx.x;   // 0..511
        for (int q = e; q < 64*128; q += 512){
            int c = q >> 7, oo = q & 127;
            w2t[q] = w2[oo*64 + c];
        }
    }
}

// identical fmaf chain used in both the max pass and the recompute pass so
// values are bit-identical.
__device__ __forceinline__ float pd_calc(const float4 a0, const float4 a1,
                                         const float4 q0, const float4 q1)
{
    float dot = a0.x*q0.x;
    dot = fmaf(a0.y, q0.y, dot);
    dot = fmaf(a0.z, q0.z, dot);
    dot = fmaf(a0.w, q0.w, dot);
    dot = fmaf(a1.x, q1.x, dot);
    dot = fmaf(a1.y, q1.y, dot);
    return fmaf(2.f, dot, -a1.z - q1.z);
}

// monotone float<->uint key transform (order-preserving, exact)
__device__ __forceinline__ unsigned fkey_(float f){
    unsigned u = __float_as_uint(f);
    return (u & 0x80000000u) ? ~u : (u | 0x80000000u);
}
__device__ __forceinline__ float finv_(unsigned k){
    return (k & 0x80000000u) ? __uint_as_float(k & 0x7fffffffu)
                             : __uint_as_float(~k);
}

// ---------------- K2: top-20 (as a SET; downstream is order-invariant) ----------------
#define TK_CAP 384
__global__ __launch_bounds__(256) void k_topk(const float* __restrict__ xtp,
                                              int* __restrict__ idxout)
{
    __shared__ float maxs[4][256];
    __shared__ float candv[4][TK_CAP];
    __shared__ int   candi[4][TK_CAP];
    __shared__ float Ts[4];
    __shared__ unsigned ccnt[4], ocnt[4], nwork;
    __shared__ unsigned short work[1024];

    const int t = threadIdx.x;
    const int rowbase = blockIdx.x << 2;        // 4 centers per block
    const int b = rowbase >> 12;
    const float* xb = xtp + ((size_t)b << 15);  // b*4096*8

    float4 c0[4], c1[4];
    #pragma unroll
    for (int c = 0; c < 4; c++){
        const float4* p = (const float4*)(xtp + (size_t)(rowbase + c)*8);
        c0[c] = p[0]; c1[c] = p[1];
    }
    if (t < 4){ ccnt[t] = 0u; ocnt[t] = 0u; }
    if (t == 0) nwork = 0u;

    // phase 1: per-thread max over its 16 points, all 4 centers
    float mx[4] = {-INFINITY, -INFINITY, -INFINITY, -INFINITY};
    {
        const float4* qp = (const float4*)(xb + (size_t)t*8);
        for (int i = 0; i < 16; i++){
            float4 q0 = qp[0], q1 = qp[1];
            #pragma unroll
            for (int c = 0; c < 4; c++)
                mx[c] = fmaxf(mx[c], pd_calc(c0[c], c1[c], q0, q1));
            qp += 512;                          // +256 points
        }
    }
    #pragma unroll
    for (int c = 0; c < 4; c++) maxs[c][t] = mx[c];
    __syncthreads();

    const int w = t >> 6, lane = t & 63;
    {   // phase 2: exact 20th-largest of maxima via ballot binary search
        unsigned k0 = fkey_(maxs[w][lane]);
        unsigned k1 = fkey_(maxs[w][64  + lane]);
        unsigned k2 = fkey_(maxs[w][128 + lane]);
        unsigned k3 = fkey_(maxs[w][192 + lane]);
        unsigned lo = 0u;
        for (int bit = 31; bit >= 0; bit--){
            unsigned cand = lo | (1u << bit);
            int cnt = __popcll(__ballot(k0 >= cand))
                    + __popcll(__ballot(k1 >= cand))
                    + __popcll(__ballot(k2 >= cand))
                    + __popcll(__ballot(k3 >= cand));
            if (cnt >= 20) lo = cand;
        }
        if (lane == 0) Ts[w] = finv_(lo);
    }
    __syncthreads();

    // phase 3a: compact worklist of qualifying (center, src-thread)
    #pragma unroll
    for (int c = 0; c < 4; c++){
        if (mx[c] >= Ts[c]){
            unsigned pos = atomicAdd(&nwork, 1u);
            work[pos] = (unsigned short)((c << 8) | t);
        }
    }
    __syncthreads();

    // phase 3b: dense recompute; push candidates >= threshold
    {
        int total = (int)nwork << 4;
        for (int e = t; e < total; e += 256){
            int ct = work[e >> 4];
            int c = ct >> 8, src = ct & 255;
            int m = ((e & 15) << 8) | src;
            const float4* p = (const float4*)(xb + (size_t)m*8);
            float4 q0 = p[0], q1 = p[1];
            float pd = pd_calc(c0[c], c1[c], q0, q1);
            if (pd >= Ts[c]){
                unsigned pos = atomicAdd(&ccnt[c], 1u);
                if (pos < TK_CAP){ candv[c][pos] = pd; candi[c][pos] = m; }
            }
        }
    }
    __syncthreads();

    {   // phase 4: exact top-20 set of center w's candidates
        int n = (int)min(ccnt[w], (unsigned)TK_CAP);
        unsigned key[6]; int id[6];
        #pragma unroll
        for (int j = 0; j < 6; j++){
            int p = (j << 6) | lane;
            bool ok = p < n;
            key[j] = ok ? fkey_(candv[w][p]) : 0u;     // 0 < any finite key
            id[j]  = ok ? candi[w][p] : 0x7fffffff;
        }
        unsigned C = 0u;                               // cutoff key (20th largest)
        for (int bit = 31; bit >= 0; bit--){
            unsigned cand = C | (1u << bit);
            int cnt = 0;
            #pragma unroll
            for (int j = 0; j < 6; j++)
                cnt += __popcll(__ballot(key[j] >= cand));
            if (cnt >= 20) C = cand;
        }
        int m = 0, e = 0;
        #pragma unroll
        for (int j = 0; j < 6; j++){
            m += __popcll(__ballot(key[j] > C));
            e += __popcll(__ballot(key[j] == C));
        }
        int* outp = idxout + (size_t)(rowbase + w)*20;
        #pragma unroll
        for (int j = 0; j < 6; j++){
            if (key[j] > C){
                unsigned pos = atomicAdd(&ocnt[w], 1u);
                outp[pos] = id[j];
            }
        }
        int need = 20 - m;                             // >= 1; e >= need always
        if (e <= need){                                // no boundary tie surplus
            #pragma unroll
            for (int j = 0; j < 6; j++){
                if (key[j] == C){
                    unsigned pos = atomicAdd(&ocnt[w], 1u);
                    outp[pos] = id[j];
                }
            }
        } else {                                       // rare: ties at cutoff
            for (int r = 0; r < need; r++){
                int loc = 0x7fffffff;
                #pragma unroll
                for (int j = 0; j < 6; j++)
                    if (key[j] == C && id[j] < loc) loc = id[j];
                int g = loc;
                #pragma unroll
                for (int s = 1; s < 64; s <<= 1) g = min(g, __shfl_xor(g, s));
                #pragma unroll
                for (int j = 0; j < 6; j++){
                    if (key[j] == C && id[j] == g){
                        key[j] = 0u;                   // remove; emit once
                        unsigned pos = atomicAdd(&ocnt[w], 1u);
                        outp[pos] = g;
                    }
                }
            }
        }
    }
}

// ---------------- K3: bn1 stats ----------------
__global__ __launch_bounds__(256) void k_bn1stats(const float* __restrict__ xtp,
                                                  const int* __restrict__ idxb,
                                                  const float* __restrict__ w1,
                                                  float* __restrict__ bn1sum,
                                                  float* __restrict__ bn1sq)
{
    __shared__ float fT[320*12];                // 16 rows * 20 nbrs * 12
    __shared__ float red[2][4][64];
    const int t = threadIdx.x;
    const int rowbase = blockIdx.x << 4;        // 16 rows
    const int b = rowbase >> 12;

    for (int s = t; s < 320; s += 256){
        int r = s / 20, k = s % 20;
        int grow = rowbase + r;
        int m = idxb[(size_t)grow*20 + k];
        const float4* pn = (const float4*)(xtp + (size_t)((b << 12) | m)*8);
        const float4* pc = (const float4*)(xtp + (size_t)grow*8);
        float4 n0 = pn[0], n1 = pn[1], c0 = pc[0], c1 = pc[1];
        float* f = fT + s*12;
        ((float4*)f)[0] = make_float4(n0.x-c0.x, n0.y-c0.y, n0.z-c0.z, n0.w-c0.w);
        ((float4*)f)[1] = make_float4(n1.x-c1.x, n1.y-c1.y, c0.x, c0.y);
        ((float4*)f)[2] = make_float4(c0.z, c0.w, c1.x, c1.y);
    }
    __syncthreads();
    const int o = t & 63, grp = t >> 6;
    float w[12];
    #pragma unroll
    for (int c = 0; c < 12; c++) w[c] = w1[o*12 + c];
    float sm = 0.f, sq = 0.f;
    for (int s = grp*80; s < grp*80 + 80; s++){
        const float* f = fT + s*12;
        float4 f0 = *(const float4*)(f);
        float4 fa = *(const float4*)(f + 4);
        float4 fb = *(const float4*)(f + 8);
        float h = w[0]*f0.x + w[1]*f0.y + w[2]*f0.z + w[3]*f0.w
                + w[4]*fa.x + w[5]*fa.y + w[6]*fa.z + w[7]*fa.w
                + w[8]*fb.x + w[9]*fb.y + w[10]*fb.z + w[11]*fb.w;
        sm += h; sq = fmaf(h, h, sq);
    }
    red[0][grp][o] = sm; red[1][grp][o] = sq;
    __syncthreads();
    if (t < 64){
        float a = red[0][0][t] + red[0][1][t] + red[0][2][t] + red[0][3][t];
        float c2 = red[1][0][t] + red[1][1][t] + red[1][2][t] + red[1][3][t];
        atomicAdd(bn1sum + t, a);
        atomicAdd(bn1sq + t, c2);
    }
}

// ---------------- generic BN finalize ----------------
__global__ void k_bnfin(const float* __restrict__ sum, const float* __restrict__ sq,
                        const float* __restrict__ gamma, const float* __restrict__ beta,
                        float* __restrict__ st, int C, float invN)
{
    int o = threadIdx.x;
    if (o < C){
        float mean = sum[o]*invN;
        float var  = sq[o]*invN - mean*mean;
        float s = gamma[o]/sqrtf(var + EPS_);
        st[o] = s;
        st[C + o] = beta[o] - mean*s;
    }
}

// ---------------- K4: fused conv1+bn1+lrelu+conv2 -> max_k + bn2 stats ----------------
// Best-measured conv12 (231 us): 5 vec x 8 o register tile, f1s XOR-swizzled,
// w2 panels at 516-word stride staged via linear global read. Epilogue scratch
// in w2u [3 stats][16 qr][128 o]. NOTE: conflict counter ~23.6M here but time
// is conflict-insensitive (R6-R9 sweep: 231-245 us across 0-23.6M conflicts).
__global__ __launch_bounds__(256, 3) void k_conv12(
    const float* __restrict__ xtp, const int* __restrict__ idxb,
    const float* __restrict__ w1, const float* __restrict__ w2t,
    const float* __restrict__ bn1st,
    float* __restrict__ h2max, float* __restrict__ bn2sum, float* __restrict__ bn2sq)
{
    __shared__ float f1s[80*64];        // 20480 B  conv1 out, XOR-swizzled j
    __shared__ float w2u[16*516];       // 33024 B  w2 panels; fT alias; scratch alias
    const int t = threadIdx.x;
    const int rowbase = blockIdx.x << 2;
    const int b = rowbase >> 12;

    // w1 row into regs (j = t&63 owns output channel j)
    const int jch = t & 63;
    float wr[12];
    #pragma unroll
    for (int c = 0; c < 12; c++) wr[c] = w1[jch*12 + c];

    float* fT = w2u;                    // fT[80][12] aliases first 960 floats of w2u
    if (t < 80){
        int r = t / 20;
        int grow = rowbase + r;
        int m = idxb[(size_t)grow*20 + (t - r*20)];
        const float4* pn = (const float4*)(xtp + (size_t)((b << 12) | m)*8);
        const float4* pc = (const float4*)(xtp + (size_t)grow*8);
        float4 n0 = pn[0], n1 = pn[1], c0 = pc[0], c1 = pc[1];
        float* f = fT + t*12;
        ((float4*)f)[0] = make_float4(n0.x-c0.x, n0.y-c0.y, n0.z-c0.z, n0.w-c0.w);
        ((float4*)f)[1] = make_float4(n1.x-c1.x, n1.y-c1.y, c0.x, c0.y);
        ((float4*)f)[2] = make_float4(c0.z, c0.w, c1.x, c1.y);
    }
    __syncthreads();                    // sync1: fT ready
    {   // conv1 + bn1 + lrelu -> f1s (XOR-swizzled j within each vec row)
        const float s1 = bn1st[jch], t1 = bn1st[64 + jch];
        for (int vid = t; vid < 5120; vid += 256){
            int vec = vid >> 6;
            const float* f = fT + vec*12;
            float4 f0 = *(const float4*)(f);
            float4 fa = *(const float4*)(f + 4);
            float4 fb = *(const float4*)(f + 8);
            float acc = wr[0]*f0.x + wr[1]*f0.y + wr[2]*f0.z + wr[3]*f0.w
                      + wr[4]*fa.x + wr[5]*fa.y + wr[6]*fa.z + wr[7]*fa.w
                      + wr[8]*fb.x + wr[9]*fb.y + wr[10]*fb.z + wr[11]*fb.w;
            float v = fmaf(s1, acc, t1);
            f1s[(vec << 6) + (jch ^ ((vec & 7) << 2))] = fmaxf(v, 0.2f*v);
        }
    }
    __syncthreads();                    // sync2: f1s ready, fT dead
    {   // short-liveness copy w2t -> w2u panels (linear coalesced global read)
        float4 tmp[8];
        #pragma unroll
        for (int i = 0; i < 8; i++) tmp[i] = ((const float4*)w2t)[t + (i << 8)];
        #pragma unroll
        for (int i = 0; i < 8; i++){
            int q = t + (i << 8);               // float4 id
            int jr = q >> 5, o4 = q & 31;
            *(float4*)&w2u[(o4 >> 1)*516 + (jr << 3) + ((o4 & 1) << 2)] = tmp[i];
        }
    }
    __syncthreads();                    // sync3: w2u ready

    // conv2: thread = (vg owns 5 vecs of row r=vg>>2, og owns 8 o's)
    const int vg = t & 15, og = t >> 4;
    const float* fp = f1s + vg*5*64;
    const float* wp = w2u + og*516;
    int xw[5];
    #pragma unroll
    for (int i = 0; i < 5; i++) xw[i] = ((vg*5 + i) & 7) << 2;

    float h[5][8];
    #pragma unroll
    for (int i = 0; i < 5; i++)
        #pragma unroll
        for (int oi = 0; oi < 8; oi++) h[i][oi] = 0.f;

    #pragma unroll
    for (int jl = 0; jl < 64; jl += 4){
        float wv[4][8];
        #pragma unroll
        for (int jj = 0; jj < 4; jj++){
            *(float4*)&wv[jj][0] = *(const float4*)&wp[((jl + jj) << 3)];
            *(float4*)&wv[jj][4] = *(const float4*)&wp[((jl + jj) << 3) + 4];
        }
        #pragma unroll
        for (int i = 0; i < 5; i++){
            float fv[4];
            *(float4*)fv = *(const float4*)&fp[(i << 6) + (jl ^ xw[i])];
            #pragma unroll
            for (int jj = 0; jj < 4; jj++)
                #pragma unroll
                for (int oi = 0; oi < 8; oi++)
                    h[i][oi] = fmaf(fv[jj], wv[jj][oi], h[i][oi]);
        }
    }

    // fold the 5 k's in-register
    float mxl[8], sml[8], sql[8];
    #pragma unroll
    for (int oi = 0; oi < 8; oi++){
        float v = h[0][oi];
        mxl[oi] = v; sml[oi] = v; sql[oi] = v*v;
    }
    #pragma unroll
    for (int i = 1; i < 5; i++)
        #pragma unroll
        for (int oi = 0; oi < 8; oi++){
            float v = h[i][oi];
            mxl[oi] = fmaxf(mxl[oi], v);
            sml[oi] += v;
            sql[oi] = fmaf(v, v, sql[oi]);
        }
    __syncthreads();                    // sync4: f1s+w2u reusable
    {   // scratch in w2u: [3 stats][16 qr][128 o]
        const int r = vg >> 2, q = vg & 3;
        int base = (((q << 2) | r) << 7) + (og << 3);
        *(float4*)&w2u[base]        = *(float4*)&mxl[0];
        *(float4*)&w2u[base + 4]    = *(float4*)&mxl[4];
        *(float4*)&w2u[2048 + base]     = *(float4*)&sml[0];
        *(float4*)&w2u[2048 + base + 4] = *(float4*)&sml[4];
        *(float4*)&w2u[4096 + base]     = *(float4*)&sql[0];
        *(float4*)&w2u[4096 + base + 4] = *(float4*)&sql[4];
    }
    __syncthreads();                    // sync5
    for (int it = t; it < 512; it += 256){
        int r = it >> 7, o = it & 127;
        float m = w2u[(r << 7) + o];
        #pragma unroll
        for (int q = 1; q < 4; q++) m = fmaxf(m, w2u[(((q << 2) | r) << 7) + o]);
        h2max[(size_t)(rowbase + r)*128 + o] = m;
    }
    if (t < 128){
        float s = 0.f, qq = 0.f;
        #pragma unroll
        for (int u = 0; u < 16; u++){
            s  += w2u[2048 + (u << 7) + t];
            qq += w2u[4096 + (u << 7) + t];
        }
        atomicAdd(bn2sum + t, s);
        atomicAdd(bn2sq + t, qq);
    }
}

// ---------------- w3 transpose into dead xtp region ----------------
__global__ __launch_bounds__(256) void k_wt3(const float* __restrict__ w3,
                                             float* __restrict__ w3t)
{
    int i = blockIdx.x*256 + threadIdx.x;       // 0..131071
    int j = i >> 10, o = i & 1023;
    w3t[i] = w3[(size_t)o*128 + j];             // w3t[j][o]
}

// ---------------- K5: bn2+lrelu+conv3 -> bn3 stats + max over n ----------------
// 64 rows/block (8192 blocks): 4r x 4o per-thread tile (FMA:ds 8:1, was 5.3:1),
// w3s stagings halved, each XCD maps to exactly one batch (2MB h2max slice
// L2-resident; 16 consecutive blocks share one f2 source). LDS 65KB -> 2/CU.
__global__ __launch_bounds__(256, 2) void k_conv3(const float* __restrict__ h2max,
    const float* __restrict__ bn2st, const float* __restrict__ w3t,
    float* __restrict__ bn3sum, float* __restrict__ bn3sq, unsigned int* __restrict__ gkey)
{
    __shared__ float f2[64*132];        // 33792 B (pad 132; also scratch)
    __shared__ float w3s[8192];         // 32768 B  [j=128][o=64] linear
    const int t = threadIdx.x;
    // XCD-contiguous remap: bid&7 -> XCD; each XCD owns one batch (rt 0..63 local)
    const int bid = blockIdx.x;                 // 0..8191
    const int idx = bid >> 3;                   // 0..1023
    const int rt = (bid & 7)*64 + (idx >> 4);   // 512 row tiles of 64
    const int ot = idx & 15;                    // 16 o-tiles of 64
    const int rowbase = rt << 6;
    const int obase = ot << 6;
    const int b = rowbase >> 12;

    for (int e = t; e < 64*128; e += 256){
        int r = e >> 7, c = e & 127;
        float v = h2max[(size_t)(rowbase + r)*128 + c];
        float u = fmaf(bn2st[c], v, bn2st[128 + c]);
        f2[r*132 + c] = fmaxf(u, 0.2f*u);
    }
    {   // short-liveness copy of w3 panel -> w3s
        float4 tmp[8];
        #pragma unroll
        for (int i = 0; i < 8; i++){
            int q = t + (i << 8);               // 0..2047
            tmp[i] = *(const float4*)&w3t[(size_t)(q >> 4)*1024 + obase + ((q & 15) << 2)];
        }
        #pragma unroll
        for (int i = 0; i < 8; i++) ((float4*)w3s)[t + (i << 8)] = tmp[i];
    }
    __syncthreads();                    // sync1: f2 + w3s ready

    const int oq = t & 15, rg = t >> 4;
    const int o0 = oq << 2, r0 = rg << 2;       // 4 rows, 4 o per thread
    float h[4][4];
    #pragma unroll
    for (int rr = 0; rr < 4; rr++)
        #pragma unroll
        for (int oi = 0; oi < 4; oi++) h[rr][oi] = 0.f;

    for (int jl = 0; jl < 128; jl += 4){
        float wv[4][4];
        #pragma unroll
        for (int jj = 0; jj < 4; jj++)
            *(float4*)wv[jj] = *(const float4*)&w3s[(jl + jj)*64 + o0];
        float fr[4][4];
        #pragma unroll
        for (int rr = 0; rr < 4; rr++)
            *(float4*)fr[rr] = *(const float4*)&f2[(r0 + rr)*132 + jl];
        #pragma unroll
        for (int jj = 0; jj < 4; jj++)
            #pragma unroll
            for (int rr = 0; rr < 4; rr++)
                #pragma unroll
                for (int oi = 0; oi < 4; oi++)
                    h[rr][oi] = fmaf(fr[rr][jj], wv[jj][oi], h[rr][oi]);
    }

    // fold 4 rows in-register
    float sml[4], sql[4], mxl[4];
    #pragma unroll
    for (int oi = 0; oi < 4; oi++){
        float v = h[0][oi];
        sml[oi] = v; sql[oi] = v*v; mxl[oi] = v;
    }
    #pragma unroll
    for (int rr = 1; rr < 4; rr++)
        #pragma unroll
        for (int oi = 0; oi < 4; oi++){
            float v = h[rr][oi];
            sml[oi] += v;
            sql[oi] = fmaf(v, v, sql[oi]);
            mxl[oi] = fmaxf(mxl[oi], v);
        }
    __syncthreads();                    // sync2: f2 reusable as scratch
    float* scr = f2;                    // [3][16 rg][64 o]
    *(float4*)&scr[(rg << 6) + o0]        = *(float4*)&sml[0];
    *(float4*)&scr[1024 + (rg << 6) + o0] = *(float4*)&sql[0];
    *(float4*)&scr[2048 + (rg << 6) + o0] = *(float4*)&mxl[0];
    __syncthreads();                    // sync3
    if (t < 192){
        int stat = t >> 6, o = t & 63;
        if (stat == 0){
            float s = 0.f;
            #pragma unroll
            for (int g2 = 0; g2 < 16; g2++) s += scr[(g2 << 6) + o];
            atomicAdd(bn3sum + obase + o, s);
        } else if (stat == 1){
            float s = 0.f;
            #pragma unroll
            for (int g2 = 0; g2 < 16; g2++) s += scr[1024 + (g2 << 6) + o];
            atomicAdd(bn3sq + obase + o, s);
        } else {
            float m = scr[2048 + o];
            #pragma unroll
            for (int g2 = 1; g2 < 16; g2++) m = fmaxf(m, scr[2048 + (g2 << 6) + o]);
            unsigned u = __float_as_uint(m);
            unsigned key = (u & 0x80000000u) ? ~u : (u | 0x80000000u);
            atomicMax(gkey + (b << 10) + obase + o, key);
        }
    }
}

// ---------------- K5f: finalize bn3 + g = lrelu(bn3(gmax)) ----------------
__global__ void k_bn3g(const float* __restrict__ sum, const float* __restrict__ sq,
                       const unsigned int* __restrict__ gkey,
                       const float* __restrict__ gamma, const float* __restrict__ beta,
                       float* __restrict__ g)
{
    int o = blockIdx.x*256 + threadIdx.x;
    if (o < 1024){
        float mean = sum[o]*(1.f/32768.f);
        float var  = sq[o]*(1.f/32768.f) - mean*mean;
        float s = gamma[o]/sqrtf(var + EPS_);
        float tt = beta[o] - mean*s;
        for (int b = 0; b < 8; b++){
            unsigned k = gkey[(b << 10) + o];
            unsigned u = (k & 0x80000000u) ? (k & 0x7fffffffu) : ~k;
            float v = __uint_as_float(u);
            float xv = fmaf(s, v, tt);
            g[(b << 10) + o] = fmaxf(xv, 0.2f*xv);
        }
    }
}

// ---------------- FC: one wave per output ----------------
__global__ __launch_bounds__(256) void k_fc(const float* __restrict__ in,
                                            const float* __restrict__ w,
                                            float* __restrict__ out, int Kdim, int Odim)
{
    int wid = (blockIdx.x*256 + threadIdx.x) >> 6;
    int lane = threadIdx.x & 63;
    int nout = 8*Odim;
    if (wid >= nout) return;
    int b = wid / Odim, o = wid - b*Odim;
    const float* gi = in + (size_t)b*Kdim;
    const float* wr = w + (size_t)o*Kdim;
    float acc = 0.f;
    for (int c = lane; c < Kdim; c += 64) acc = fmaf(gi[c], wr[c], acc);
    #pragma unroll
    for (int s = 32; s > 0; s >>= 1) acc += __shfl_xor(acc, s);
    if (lane == 0) out[(size_t)b*Odim + o] = acc;
}

// ---------------- batch-BN (over B=8) + lrelu ----------------
__global__ void k_bnb(const float* __restrict__ h, const float* __restrict__ gamma,
                      const float* __restrict__ beta, float* __restrict__ g, int C)
{
    int o = blockIdx.x*256 + threadIdx.x;
    if (o < C){
        float s = 0.f, q = 0.f;
        for (int b = 0; b < 8; b++){ float v = h[(size_t)b*C + o]; s += v; q = fmaf(v, v, q); }
        float mean = s*0.125f;
        float var  = q*0.125f - mean*mean;
        float sc = gamma[o]/sqrtf(var + EPS_);
        float tt = beta[o] - mean*sc;
        for (int b = 0; b < 8; b++){
            float xv = fmaf(sc, h[(size_t)b*C + o], tt);
            g[(size_t)b*C + o] = fmaxf(xv, 0.2f*xv);
        }
    }
}

// ---------------- head: fc3 (-> I + 3x3) and fc4 (-> bias) ----------------
__global__ void k_head(const float* __restrict__ g5,
                       const float* __restrict__ fc3w, const float* __restrict__ fc3b,
                       const float* __restrict__ fc4w, const float* __restrict__ fc4b,
                       float* __restrict__ mat, float* __restrict__ bias3)
{
    int t = threadIdx.x;
    if (t < 96){
        int b = t / 12, j = t % 12;
        const float* gi = g5 + b*256;
        if (j < 9){
            const float* w = fc3w + j*256;
            float a = fc3b[j];
            for (int c = 0; c < 256; c++) a = fmaf(gi[c], w[c], a);
            if (j == 0 || j == 4 || j == 8) a += 1.f;
            mat[b*9 + j] = a;
        } else {
            int d = j - 9;
            const float* w = fc4w + d*256;
            float a = fc4b[d];
            for (int c = 0; c < 256; c++) a = fmaf(gi[c], w[c], a);
            bias3[b*3 + d] = a;
        }
    }
}

// ---------------- final transform: out[b,d,n] ----------------
__global__ __launch_bounds__(256) void k_out(const float* __restrict__ x,
                                             const float* __restrict__ mat,
                                             const float* __restrict__ bias3,
                                             float* __restrict__ out)
{
    int i = blockIdx.x*256 + threadIdx.x;       // 0..98303
    int n = i & 4095, bd = i >> 12;
    int b = bd / 3, d = bd - b*3;
    const float* xb = x + (size_t)b*6*4096 + n;
    const float* M = mat + b*9;
    out[i] = xb[0]*M[d] + xb[4096]*M[3 + d] + xb[2*4096]*M[6 + d] + bias3[b*3 + d];
}

// ---------------- launch ----------------
extern "C" void kernel_launch(void* const* d_in, const int* in_sizes, int n_in,
                              void* d_out, int out_size, void* d_ws, size_t ws_size,
                              hipStream_t stream)
{
    const float* x     = (const float*)d_in[0];
    const float* w1    = (const float*)d_in[1];
    const float* bn1g  = (const float*)d_in[2];
    const float* bn1b  = (const float*)d_in[3];
    const float* w2    = (const float*)d_in[4];
    const float* bn2g  = (const float*)d_in[5];
    const float* bn2b  = (const float*)d_in[6];
    const float* w3    = (const float*)d_in[7];
    const float* bn3gm = (const float*)d_in[8];
    const float* bn3bt = (const float*)d_in[9];
    const float* fc1w  = (const float*)d_in[10];
    const float* bn4g  = (const float*)d_in[11];
    const float* bn4b  = (const float*)d_in[12];
    const float* fc2w  = (const float*)d_in[13];
    const float* bn5g  = (const float*)d_in[14];
    const float* bn5b  = (const float*)d_in[15];
    const float* fc3w  = (const float*)d_in[16];
    const float* fc3b  = (const float*)d_in[17];
    const float* fc4w  = (const float*)d_in[18];
    const float* fc4b  = (const float*)d_in[19];
    float* out = (float*)d_out;

    char* ws = (char*)d_ws;
    float* xtp   = (float*)(ws);
    float* w3t_g = (float*)(ws);                 // overwrites xtp AFTER k_conv12
    int*   idxb  = (int*)  (ws + 1048576);
    float* h2max = (float*)(ws + 3670016);
    float* zs    = (float*)(ws + 20447232);
    float* bn1sum = zs;            float* bn1sq = zs + 64;
    float* bn2sum = zs + 128;      float* bn2sq = zs + 256;
    float* bn3sum = zs + 384;      float* bn3sq = zs + 1408;
    unsigned int* gkey = (unsigned int*)(zs + 2432);
    float* tail  = (float*)(ws + 20489728);
    float* bn1st = tail;           // 128
    float* bn2st = tail + 128;     // 256
    float* g     = tail + 384;     // 8192
    float* h4    = tail + 8576;    // 4096
    float* g4    = tail + 12672;   // 4096
    float* h5    = tail + 16768;   // 2048
    float* g5    = tail + 18816;   // 2048
    float* mat   = tail + 20864;   // 72
    float* bias3 = tail + 20936;   // 24
    float* w2t_g = (float*)(ws + 20573568);      // 32KB

    hipMemsetAsync(zs, 0, 42496, stream);

    k_prep    <<<128,   256, 0, stream>>>(x, xtp, w2, w2t_g);
    k_topk    <<<8192,  256, 0, stream>>>(xtp, idxb);
    k_bn1stats<<<2048,  256, 0, stream>>>(xtp, idxb, w1, bn1sum, bn1sq);
    k_bnfin   <<<1,     128, 0, stream>>>(bn1sum, bn1sq, bn1g, bn1b, bn1st, 64, 1.f/655360.f);
    k_conv12  <<<8192,  256, 0, stream>>>(xtp, idxb, w1, w2t_g, bn1st, h2max, bn2sum, bn2sq);
    k_wt3     <<<512,   256, 0, stream>>>(w3, w3t_g);
    k_bnfin   <<<1,     128, 0, stream>>>(bn2sum, bn2sq, bn2g, bn2b, bn2st, 128, 1.f/655360.f);
    k_conv3   <<<8192,  256, 0, stream>>>(h2max, bn2st, w3t_g, bn3sum, bn3sq, gkey);
    k_bn3g    <<<4,     256, 0, stream>>>(bn3sum, bn3sq, gkey, bn3gm, bn3bt, g);
    k_fc      <<<1024,  256, 0, stream>>>(g, fc1w, h4, 1024, 512);
    k_bnb     <<<2,     256, 0, stream>>>(h4, bn4g, bn4b, g4, 512);
    k_fc      <<<512,   256, 0, stream>>>(g4, fc2w, h5, 512, 256);
    k_bnb     <<<1,     256, 0, stream>>>(h5, bn5g, bn5b, g5, 256);
    k_head    <<<1,     128, 0, stream>>>(g5, fc3w, fc3b, fc4w, fc4b, mat, bias3);
    k_out     <<<384,   256, 0, stream>>>(x, mat, bias3, out);
}

// Round 11
// 725.068 us; speedup vs baseline: 1.0882x; 1.0441x over previous
//
#include <hip/hip_runtime.h>
#include <math.h>
#include <stddef.h>

// TransformNet fused pipeline, fp32.
// B=8, C=6, N=4096, K=20.
//
// ws layout (bytes):
//   [0)          xtp   : 8*4096*8 floats (points padded to 8)    1,048,576
//                        (REUSED after k_conv12 as w3t: 128x1024 = 524,288)
//   [1048576)    idx   : 8*4096*20 ints                          2,621,440
//   [3670016)    h2max : 8*4096*128 floats                      16,777,216
//   [20447232)   zstats: zero-initialized stats block                42,496
//   [20489728)   tail  : g(8192) h4(4096) g4(4096)
//                        h5(2048) g5(2048) mat(72) bias3(24)        83,840
//   [20573568)   w2t_g : 64x128 floats (w2 transposed)              32,768

static constexpr float EPS_ = 1e-5f;

// ---------------- K1: transpose-pad points + squared norms (+ w2 transpose) ----------------
__global__ __launch_bounds__(256) void k_prep(const float* __restrict__ x,
                                              float* __restrict__ xtp,
                                              const float* __restrict__ w2,
                                              float* __restrict__ w2t)
{
    int i = blockIdx.x*256 + threadIdx.x;       // 0..32767  (b*4096+n)
    int b = i >> 12, n = i & 4095;
    const float* xb = x + (size_t)b*6*4096 + n;
    float v0 = xb[0], v1 = xb[4096], v2 = xb[2*4096];
    float v3 = xb[3*4096], v4 = xb[4*4096], v5 = xb[5*4096];
    float xx = v0*v0 + v1*v1 + v2*v2 + v3*v3 + v4*v4 + v5*v5;
    float4* o = (float4*)(xtp + (size_t)i*8);
    o[0] = make_float4(v0, v1, v2, v3);
    o[1] = make_float4(v4, v5, xx, 0.f);
    if (blockIdx.x < 2){                        // w2t[c][o] = w2[o][c]
        int e = blockIdx.x*256 + threadIdx.x;   // 0..511
        for (int q = e; q < 64*128; q += 512){
            int c = q >> 7, oo = q & 127;
            w2t[q] = w2[oo*64 + c];
        }
    }
}

// identical fmaf chain used in both the max pass and the recompute pass so
// values are bit-identical.
__device__ __forceinline__ float pd_calc(const float4 a0, const float4 a1,
                                         const float4 q0, const float4 q1)
{
    float dot = a0.x*q0.x;
    dot = fmaf(a0.y, q0.y, dot);
    dot = fmaf(a0.z, q0.z, dot);
    dot = fmaf(a0.w, q0.w, dot);
    dot = fmaf(a1.x, q1.x, dot);
    dot = fmaf(a1.y, q1.y, dot);
    return fmaf(2.f, dot, -a1.z - q1.z);
}

// monotone float<->uint key transform (order-preserving, exact)
__device__ __forceinline__ unsigned fkey_(float f){
    unsigned u = __float_as_uint(f);
    return (u & 0x80000000u) ? ~u : (u | 0x80000000u);
}
__device__ __forceinline__ float finv_(unsigned k){
    return (k & 0x80000000u) ? __uint_as_float(k & 0x7fffffffu)
                             : __uint_as_float(~k);
}

// ---------------- K2: top-20 (as a SET; downstream is order-invariant) ----------------
// 8 centers per block: the 32 q-point loads/thread amortize over 8 centers
// (chip-wide phase-1 load issue halves). Phases 3/4 run in two passes of 4
// centers, reusing the candidate arrays (LDS stays ~22KB).
#define TK_CAP 384
__global__ __launch_bounds__(256) void k_topk(const float* __restrict__ xtp,
                                              int* __restrict__ idxout)
{
    __shared__ float maxs[8][256];
    __shared__ float candv[4][TK_CAP];
    __shared__ int   candi[4][TK_CAP];
    __shared__ float Ts[8];
    __shared__ unsigned ccnt[4], ocnt[4], nwork;
    __shared__ unsigned short work[1024];

    const int t = threadIdx.x;
    const int rowbase = blockIdx.x << 3;        // 8 centers per block
    const int b = rowbase >> 12;
    const float* xb = xtp + ((size_t)b << 15);  // b*4096*8

    float4 c0[8], c1[8];
    #pragma unroll
    for (int c = 0; c < 8; c++){
        const float4* p = (const float4*)(xtp + (size_t)(rowbase + c)*8);
        c0[c] = p[0]; c1[c] = p[1];
    }

    // phase 1: per-thread max over its 16 points, all 8 centers
    float mx[8];
    #pragma unroll
    for (int c = 0; c < 8; c++) mx[c] = -INFINITY;
    {
        const float4* qp = (const float4*)(xb + (size_t)t*8);
        for (int i = 0; i < 16; i++){
            float4 q0 = qp[0], q1 = qp[1];
            #pragma unroll
            for (int c = 0; c < 8; c++)
                mx[c] = fmaxf(mx[c], pd_calc(c0[c], c1[c], q0, q1));
            qp += 512;                          // +256 points
        }
    }
    #pragma unroll
    for (int c = 0; c < 8; c++) maxs[c][t] = mx[c];
    __syncthreads();

    const int w = t >> 6, lane = t & 63;
    // phase 2: exact 20th-largest of maxima via ballot binary search (2/wave)
    for (int cc = w; cc < 8; cc += 4){
        unsigned k0 = fkey_(maxs[cc][lane]);
        unsigned k1 = fkey_(maxs[cc][64  + lane]);
        unsigned k2 = fkey_(maxs[cc][128 + lane]);
        unsigned k3 = fkey_(maxs[cc][192 + lane]);
        unsigned lo = 0u;
        for (int bit = 31; bit >= 0; bit--){
            unsigned cand = lo | (1u << bit);
            int cnt = __popcll(__ballot(k0 >= cand))
                    + __popcll(__ballot(k1 >= cand))
                    + __popcll(__ballot(k2 >= cand))
                    + __popcll(__ballot(k3 >= cand));
            if (cnt >= 20) lo = cand;
        }
        if (lane == 0) Ts[cc] = finv_(lo);
    }
    __syncthreads();

    for (int p = 0; p < 2; p++){
        const int cb = p << 2;                  // center base for this pass
        if (t < 4){ ccnt[t] = 0u; ocnt[t] = 0u; }
        if (t == 0) nwork = 0u;
        __syncthreads();

        // phase 3a: compact worklist of qualifying (center, src-thread)
        #pragma unroll
        for (int c = 0; c < 4; c++){
            if (mx[cb + c] >= Ts[cb + c]){
                unsigned pos = atomicAdd(&nwork, 1u);
                work[pos] = (unsigned short)((c << 8) | t);
            }
        }
        __syncthreads();

        // phase 3b: dense recompute; push candidates >= threshold
        {
            int total = (int)nwork << 4;
            for (int e = t; e < total; e += 256){
                int ct = work[e >> 4];
                int c = ct >> 8, src = ct & 255;
                int m = ((e & 15) << 8) | src;
                const float4* pp = (const float4*)(xb + (size_t)m*8);
                float4 q0 = pp[0], q1 = pp[1];
                float pd = pd_calc(c0[cb + c], c1[cb + c], q0, q1);
                if (pd >= Ts[cb + c]){
                    unsigned pos = atomicAdd(&ccnt[c], 1u);
                    if (pos < TK_CAP){ candv[c][pos] = pd; candi[c][pos] = m; }
                }
            }
        }
        __syncthreads();

        {   // phase 4: exact top-20 set of local center w
            int n = (int)min(ccnt[w], (unsigned)TK_CAP);
            unsigned key[6]; int id[6];
            #pragma unroll
            for (int j = 0; j < 6; j++){
                int pz = (j << 6) | lane;
                bool ok = pz < n;
                key[j] = ok ? fkey_(candv[w][pz]) : 0u; // 0 < any finite key
                id[j]  = ok ? candi[w][pz] : 0x7fffffff;
            }
            unsigned C = 0u;                            // cutoff key (20th largest)
            for (int bit = 31; bit >= 0; bit--){
                unsigned cand = C | (1u << bit);
                int cnt = 0;
                #pragma unroll
                for (int j = 0; j < 6; j++)
                    cnt += __popcll(__ballot(key[j] >= cand));
                if (cnt >= 20) C = cand;
            }
            int m = 0, e = 0;
            #pragma unroll
            for (int j = 0; j < 6; j++){
                m += __popcll(__ballot(key[j] > C));
                e += __popcll(__ballot(key[j] == C));
            }
            int* outp = idxout + (size_t)(rowbase + cb + w)*20;
            #pragma unroll
            for (int j = 0; j < 6; j++){
                if (key[j] > C){
                    unsigned pos = atomicAdd(&ocnt[w], 1u);
                    outp[pos] = id[j];
                }
            }
            int need = 20 - m;                          // >= 1; e >= need always
            if (e <= need){                             // no boundary tie surplus
                #pragma unroll
                for (int j = 0; j < 6; j++){
                    if (key[j] == C){
                        unsigned pos = atomicAdd(&ocnt[w], 1u);
                        outp[pos] = id[j];
                    }
                }
            } else {                                    // rare: ties at cutoff
                for (int r = 0; r < need; r++){
                    int loc = 0x7fffffff;
                    #pragma unroll
                    for (int j = 0; j < 6; j++)
                        if (key[j] == C && id[j] < loc) loc = id[j];
                    int g = loc;
                    #pragma unroll
                    for (int s = 1; s < 64; s <<= 1) g = min(g, __shfl_xor(g, s));
                    #pragma unroll
                    for (int j = 0; j < 6; j++){
                        if (key[j] == C && id[j] == g){
                            key[j] = 0u;               // remove; emit once
                            unsigned pos = atomicAdd(&ocnt[w], 1u);
                            outp[pos] = g;
                        }
                    }
                }
            }
        }
        __syncthreads();                        // protect candv/ccnt before reset
    }
}

// ---------------- K3: bn1 stats ----------------
__global__ __launch_bounds__(256) void k_bn1stats(const float* __restrict__ xtp,
                                                  const int* __restrict__ idxb,
                                                  const float* __restrict__ w1,
                                                  float* __restrict__ bn1sum,
                                                  float* __restrict__ bn1sq)
{
    __shared__ float fT[320*12];                // 16 rows * 20 nbrs * 12
    __shared__ float red[2][4][64];
    const int t = threadIdx.x;
    const int rowbase = blockIdx.x << 4;        // 16 rows
    const int b = rowbase >> 12;

    for (int s = t; s < 320; s += 256){
        int r = s / 20, k = s % 20;
        int grow = rowbase + r;
        int m = idxb[(size_t)grow*20 + k];
        const float4* pn = (const float4*)(xtp + (size_t)((b << 12) | m)*8);
        const float4* pc = (const float4*)(xtp + (size_t)grow*8);
        float4 n0 = pn[0], n1 = pn[1], c0 = pc[0], c1 = pc[1];
        float* f = fT + s*12;
        ((float4*)f)[0] = make_float4(n0.x-c0.x, n0.y-c0.y, n0.z-c0.z, n0.w-c0.w);
        ((float4*)f)[1] = make_float4(n1.x-c1.x, n1.y-c1.y, c0.x, c0.y);
        ((float4*)f)[2] = make_float4(c0.z, c0.w, c1.x, c1.y);
    }
    __syncthreads();
    const int o = t & 63, grp = t >> 6;
    float w[12];
    #pragma unroll
    for (int c = 0; c < 12; c++) w[c] = w1[o*12 + c];
    float sm = 0.f, sq = 0.f;
    for (int s = grp*80; s < grp*80 + 80; s++){
        const float* f = fT + s*12;
        float4 f0 = *(const float4*)(f);
        float4 fa = *(const float4*)(f + 4);
        float4 fb = *(const float4*)(f + 8);
        float h = w[0]*f0.x + w[1]*f0.y + w[2]*f0.z + w[3]*f0.w
                + w[4]*fa.x + w[5]*fa.y + w[6]*fa.z + w[7]*fa.w
                + w[8]*fb.x + w[9]*fb.y + w[10]*fb.z + w[11]*fb.w;
        sm += h; sq = fmaf(h, h, sq);
    }
    red[0][grp][o] = sm; red[1][grp][o] = sq;
    __syncthreads();
    if (t < 64){
        float a = red[0][0][t] + red[0][1][t] + red[0][2][t] + red[0][3][t];
        float c2 = red[1][0][t] + red[1][1][t] + red[1][2][t] + red[1][3][t];
        atomicAdd(bn1sum + t, a);
        atomicAdd(bn1sq + t, c2);
    }
}

// ---------------- K4: fused conv1+bn1+lrelu+conv2 -> max_k + bn2 stats ----------------
// bn1 finalize inlined (per-thread, bit-identical formula; saves a launch).
// conv2 register tile 5 vec x 8 o; f1s XOR-swizzled; w2 panels at 516-word
// stride staged via linear global read. Epilogue scratch [3 stats][16 qr][128 o].
__global__ __launch_bounds__(256, 3) void k_conv12(
    const float* __restrict__ xtp, const int* __restrict__ idxb,
    const float* __restrict__ w1, const float* __restrict__ w2t,
    const float* __restrict__ bn1sum, const float* __restrict__ bn1sq,
    const float* __restrict__ bn1g, const float* __restrict__ bn1b,
    float* __restrict__ h2max, float* __restrict__ bn2sum, float* __restrict__ bn2sq)
{
    __shared__ float f1s[80*64];        // 20480 B  conv1 out, XOR-swizzled j
    __shared__ float w2u[16*516];       // 33024 B  w2 panels; fT alias; scratch alias
    const int t = threadIdx.x;
    const int rowbase = blockIdx.x << 2;
    const int b = rowbase >> 12;

    // w1 row + inline bn1 finalize (identical formula to the old k_bnfin)
    const int jch = t & 63;
    float wr[12];
    #pragma unroll
    for (int c = 0; c < 12; c++) wr[c] = w1[jch*12 + c];
    float s1, t1;
    {
        float mean = bn1sum[jch]*(1.f/655360.f);
        float var  = bn1sq[jch]*(1.f/655360.f) - mean*mean;
        s1 = bn1g[jch]/sqrtf(var + EPS_);
        t1 = bn1b[jch] - mean*s1;
    }

    float* fT = w2u;                    // fT[80][12] aliases first 960 floats of w2u
    if (t < 80){
        int r = t / 20;
        int grow = rowbase + r;
        int m = idxb[(size_t)grow*20 + (t - r*20)];
        const float4* pn = (const float4*)(xtp + (size_t)((b << 12) | m)*8);
        const float4* pc = (const float4*)(xtp + (size_t)grow*8);
        float4 n0 = pn[0], n1 = pn[1], c0 = pc[0], c1 = pc[1];
        float* f = fT + t*12;
        ((float4*)f)[0] = make_float4(n0.x-c0.x, n0.y-c0.y, n0.z-c0.z, n0.w-c0.w);
        ((float4*)f)[1] = make_float4(n1.x-c1.x, n1.y-c1.y, c0.x, c0.y);
        ((float4*)f)[2] = make_float4(c0.z, c0.w, c1.x, c1.y);
    }
    __syncthreads();                    // sync1: fT ready
    {   // conv1 + bn1 + lrelu -> f1s (XOR-swizzled j within each vec row)
        for (int vid = t; vid < 5120; vid += 256){
            int vec = vid >> 6;
            const float* f = fT + vec*12;
            float4 f0 = *(const float4*)(f);
            float4 fa = *(const float4*)(f + 4);
            float4 fb = *(const float4*)(f + 8);
            float acc = wr[0]*f0.x + wr[1]*f0.y + wr[2]*f0.z + wr[3]*f0.w
                      + wr[4]*fa.x + wr[5]*fa.y + wr[6]*fa.z + wr[7]*fa.w
                      + wr[8]*fb.x + wr[9]*fb.y + wr[10]*fb.z + wr[11]*fb.w;
            float v = fmaf(s1, acc, t1);
            f1s[(vec << 6) + (jch ^ ((vec & 7) << 2))] = fmaxf(v, 0.2f*v);
        }
    }
    __syncthreads();                    // sync2: f1s ready, fT dead
    {   // short-liveness copy w2t -> w2u panels (linear coalesced global read)
        float4 tmp[8];
        #pragma unroll
        for (int i = 0; i < 8; i++) tmp[i] = ((const float4*)w2t)[t + (i << 8)];
        #pragma unroll
        for (int i = 0; i < 8; i++){
            int q = t + (i << 8);               // float4 id
            int jr = q >> 5, o4 = q & 31;
            *(float4*)&w2u[(o4 >> 1)*516 + (jr << 3) + ((o4 & 1) << 2)] = tmp[i];
        }
    }
    __syncthreads();                    // sync3: w2u ready

    // conv2: thread = (vg owns 5 vecs of row r=vg>>2, og owns 8 o's)
    const int vg = t & 15, og = t >> 4;
    const float* fp = f1s + vg*5*64;
    const float* wp = w2u + og*516;
    int xw[5];
    #pragma unroll
    for (int i = 0; i < 5; i++) xw[i] = ((vg*5 + i) & 7) << 2;

    float h[5][8];
    #pragma unroll
    for (int i = 0; i < 5; i++)
        #pragma unroll
        for (int oi = 0; oi < 8; oi++) h[i][oi] = 0.f;

    #pragma unroll
    for (int jl = 0; jl < 64; jl += 4){
        float wv[4][8];
        #pragma unroll
        for (int jj = 0; jj < 4; jj++){
            *(float4*)&wv[jj][0] = *(const float4*)&wp[((jl + jj) << 3)];
            *(float4*)&wv[jj][4] = *(const float4*)&wp[((jl + jj) << 3) + 4];
        }
        #pragma unroll
        for (int i = 0; i < 5; i++){
            float fv[4];
            *(float4*)fv = *(const float4*)&fp[(i << 6) + (jl ^ xw[i])];
            #pragma unroll
            for (int jj = 0; jj < 4; jj++)
                #pragma unroll
                for (int oi = 0; oi < 8; oi++)
                    h[i][oi] = fmaf(fv[jj], wv[jj][oi], h[i][oi]);
        }
    }

    // fold the 5 k's in-register
    float mxl[8], sml[8], sql[8];
    #pragma unroll
    for (int oi = 0; oi < 8; oi++){
        float v = h[0][oi];
        mxl[oi] = v; sml[oi] = v; sql[oi] = v*v;
    }
    #pragma unroll
    for (int i = 1; i < 5; i++)
        #pragma unroll
        for (int oi = 0; oi < 8; oi++){
            float v = h[i][oi];
            mxl[oi] = fmaxf(mxl[oi], v);
            sml[oi] += v;
            sql[oi] = fmaf(v, v, sql[oi]);
        }
    __syncthreads();                    // sync4: f1s+w2u reusable
    {   // scratch in w2u: [3 stats][16 qr][128 o]
        const int r = vg >> 2, q = vg & 3;
        int base = (((q << 2) | r) << 7) + (og << 3);
        *(float4*)&w2u[base]        = *(float4*)&mxl[0];
        *(float4*)&w2u[base + 4]    = *(float4*)&mxl[4];
        *(float4*)&w2u[2048 + base]     = *(float4*)&sml[0];
        *(float4*)&w2u[2048 + base + 4] = *(float4*)&sml[4];
        *(float4*)&w2u[4096 + base]     = *(float4*)&sql[0];
        *(float4*)&w2u[4096 + base + 4] = *(float4*)&sql[4];
    }
    __syncthreads();                    // sync5
    for (int it = t; it < 512; it += 256){
        int r = it >> 7, o = it & 127;
        float m = w2u[(r << 7) + o];
        #pragma unroll
        for (int q = 1; q < 4; q++) m = fmaxf(m, w2u[(((q << 2) | r) << 7) + o]);
        h2max[(size_t)(rowbase + r)*128 + o] = m;
    }
    if (t < 128){
        float s = 0.f, qq = 0.f;
        #pragma unroll
        for (int u = 0; u < 16; u++){
            s  += w2u[2048 + (u << 7) + t];
            qq += w2u[4096 + (u << 7) + t];
        }
        atomicAdd(bn2sum + t, s);
        atomicAdd(bn2sq + t, qq);
    }
}

// ---------------- w3 transpose into dead xtp region ----------------
__global__ __launch_bounds__(256) void k_wt3(const float* __restrict__ w3,
                                             float* __restrict__ w3t)
{
    int i = blockIdx.x*256 + threadIdx.x;       // 0..131071
    int j = i >> 10, o = i & 1023;
    w3t[i] = w3[(size_t)o*128 + j];             // w3t[j][o]
}

// ---------------- K5: bn2+lrelu+conv3 -> bn3 stats + max over n ----------------
// bn2 finalize inlined into LDS (saves a launch). 64 rows/block; 4r x 4o
// per-thread tile; XCD-per-batch block remap. LDS ~67.6KB -> 2/CU.
__global__ __launch_bounds__(256, 2) void k_conv3(const float* __restrict__ h2max,
    const float* __restrict__ bn2sum, const float* __restrict__ bn2sq,
    const float* __restrict__ bn2g, const float* __restrict__ bn2b,
    const float* __restrict__ w3t,
    float* __restrict__ bn3sum, float* __restrict__ bn3sq, unsigned int* __restrict__ gkey)
{
    __shared__ float f2[64*132];        // 33792 B (pad 132; also scratch)
    __shared__ float w3s[8192];         // 32768 B  [j=128][o=64] linear
    __shared__ float bn2stL[256];       //  1024 B  inline bn2 finalize
    const int t = threadIdx.x;
    // XCD-contiguous remap: bid&7 -> XCD; each XCD owns one batch
    const int bid = blockIdx.x;                 // 0..8191
    const int idx = bid >> 3;                   // 0..1023
    const int rt = (bid & 7)*64 + (idx >> 4);   // 512 row tiles of 64
    const int ot = idx & 15;                    // 16 o-tiles of 64
    const int rowbase = rt << 6;
    const int obase = ot << 6;
    const int b = rowbase >> 12;

    if (t < 128){                       // identical formula to old k_bnfin
        float mean = bn2sum[t]*(1.f/655360.f);
        float var  = bn2sq[t]*(1.f/655360.f) - mean*mean;
        float s = bn2g[t]/sqrtf(var + EPS_);
        bn2stL[t] = s;
        bn2stL[128 + t] = bn2b[t] - mean*s;
    }
    __syncthreads();                    // bn2stL ready

    for (int e = t; e < 64*128; e += 256){
        int r = e >> 7, c = e & 127;
        float v = h2max[(size_t)(rowbase + r)*128 + c];
        float u = fmaf(bn2stL[c], v, bn2stL[128 + c]);
        f2[r*132 + c] = fmaxf(u, 0.2f*u);
    }
    {   // short-liveness copy of w3 panel -> w3s
        float4 tmp[8];
        #pragma unroll
        for (int i = 0; i < 8; i++){
            int q = t + (i << 8);               // 0..2047
            tmp[i] = *(const float4*)&w3t[(size_t)(q >> 4)*1024 + obase + ((q & 15) << 2)];
        }
        #pragma unroll
        for (int i = 0; i < 8; i++) ((float4*)w3s)[t + (i << 8)] = tmp[i];
    }
    __syncthreads();                    // sync1: f2 + w3s ready

    const int oq = t & 15, rg = t >> 4;
    const int o0 = oq << 2, r0 = rg << 2;       // 4 rows, 4 o per thread
    float h[4][4];
    #pragma unroll
    for (int rr = 0; rr < 4; rr++)
        #pragma unroll
        for (int oi = 0; oi < 4; oi++) h[rr][oi] = 0.f;

    for (int jl = 0; jl < 128; jl += 4){
        float wv[4][4];
        #pragma unroll
        for (int jj = 0; jj < 4; jj++)
            *(float4*)wv[jj] = *(const float4*)&w3s[(jl + jj)*64 + o0];
        float fr[4][4];
        #pragma unroll
        for (int rr = 0; rr < 4; rr++)
            *(float4*)fr[rr] = *(const float4*)&f2[(r0 + rr)*132 + jl];
        #pragma unroll
        for (int jj = 0; jj < 4; jj++)
            #pragma unroll
            for (int rr = 0; rr < 4; rr++)
                #pragma unroll
                for (int oi = 0; oi < 4; oi++)
                    h[rr][oi] = fmaf(fr[rr][jj], wv[jj][oi], h[rr][oi]);
    }

    // fold 4 rows in-register
    float sml[4], sql[4], mxl[4];
    #pragma unroll
    for (int oi = 0; oi < 4; oi++){
        float v = h[0][oi];
        sml[oi] = v; sql[oi] = v*v; mxl[oi] = v;
    }
    #pragma unroll
    for (int rr = 1; rr < 4; rr++)
        #pragma unroll
        for (int oi = 0; oi < 4; oi++){
            float v = h[rr][oi];
            sml[oi] += v;
            sql[oi] = fmaf(v, v, sql[oi]);
            mxl[oi] = fmaxf(mxl[oi], v);
        }
    __syncthreads();                    // sync2: f2 reusable as scratch
    float* scr = f2;                    // [3][16 rg][64 o]
    *(float4*)&scr[(rg << 6) + o0]        = *(float4*)&sml[0];
    *(float4*)&scr[1024 + (rg << 6) + o0] = *(float4*)&sql[0];
    *(float4*)&scr[2048 + (rg << 6) + o0] = *(float4*)&mxl[0];
    __syncthreads();                    // sync3
    if (t < 192){
        int stat = t >> 6, o = t & 63;
        if (stat == 0){
            float s = 0.f;
            #pragma unroll
            for (int g2 = 0; g2 < 16; g2++) s += scr[(g2 << 6) + o];
            atomicAdd(bn3sum + obase + o, s);
        } else if (stat == 1){
            float s = 0.f;
            #pragma unroll
            for (int g2 = 0; g2 < 16; g2++) s += scr[1024 + (g2 << 6) + o];
            atomicAdd(bn3sq + obase + o, s);
        } else {
            float m = scr[2048 + o];
            #pragma unroll
            for (int g2 = 1; g2 < 16; g2++) m = fmaxf(m, scr[2048 + (g2 << 6) + o]);
            unsigned u = __float_as_uint(m);
            unsigned key = (u & 0x80000000u) ? ~u : (u | 0x80000000u);
            atomicMax(gkey + (b << 10) + obase + o, key);
        }
    }
}

// ---------------- K5f: finalize bn3 + g = lrelu(bn3(gmax)) ----------------
__global__ void k_bn3g(const float* __restrict__ sum, const float* __restrict__ sq,
                       const unsigned int* __restrict__ gkey,
                       const float* __restrict__ gamma, const float* __restrict__ beta,
                       float* __restrict__ g)
{
    int o = blockIdx.x*256 + threadIdx.x;
    if (o < 1024){
        float mean = sum[o]*(1.f/32768.f);
        float var  = sq[o]*(1.f/32768.f) - mean*mean;
        float s = gamma[o]/sqrtf(var + EPS_);
        float tt = beta[o] - mean*s;
        for (int b = 0; b < 8; b++){
            unsigned k = gkey[(b << 10) + o];
            unsigned u = (k & 0x80000000u) ? (k & 0x7fffffffu) : ~k;
            float v = __uint_as_float(u);
            float xv = fmaf(s, v, tt);
            g[(b << 10) + o] = fmaxf(xv, 0.2f*xv);
        }
    }
}

// ---------------- FC: one wave per output ----------------
__global__ __launch_bounds__(256) void k_fc(const float* __restrict__ in,
                                            const float* __restrict__ w,
                                            float* __restrict__ out, int Kdim, int Odim)
{
    int wid = (blockIdx.x*256 + threadIdx.x) >> 6;
    int lane = threadIdx.x & 63;
    int nout = 8*Odim;
    if (wid >= nout) return;
    int b = wid / Odim, o = wid - b*Odim;
    const float* gi = in + (size_t)b*Kdim;
    const float* wr = w + (size_t)o*Kdim;
    float acc = 0.f;
    for (int c = lane; c < Kdim; c += 64) acc = fmaf(gi[c], wr[c], acc);
    #pragma unroll
    for (int s = 32; s > 0; s >>= 1) acc += __shfl_xor(acc, s);
    if (lane == 0) out[(size_t)b*Odim + o] = acc;
}

// ---------------- batch-BN (over B=8) + lrelu ----------------
__global__ void k_bnb(const float* __restrict__ h, const float* __restrict__ gamma,
                      const float* __restrict__ beta, float* __restrict__ g, int C)
{
    int o = blockIdx.x*256 + threadIdx.x;
    if (o < C){
        float s = 0.f, q = 0.f;
        for (int b = 0; b < 8; b++){ float v = h[(size_t)b*C + o]; s += v; q = fmaf(v, v, q); }
        float mean = s*0.125f;
        float var  = q*0.125f - mean*mean;
        float sc = gamma[o]/sqrtf(var + EPS_);
        float tt = beta[o] - mean*sc;
        for (int b = 0; b < 8; b++){
            float xv = fmaf(sc, h[(size_t)b*C + o], tt);
            g[(size_t)b*C + o] = fmaxf(xv, 0.2f*xv);
        }
    }
}

// ---------------- head: fc3 (-> I + 3x3) and fc4 (-> bias) ----------------
__global__ void k_head(const float* __restrict__ g5,
                       const float* __restrict__ fc3w, const float* __restrict__ fc3b,
                       const float* __restrict__ fc4w, const float* __restrict__ fc4b,
                       float* __restrict__ mat, float* __restrict__ bias3)
{
    int t = threadIdx.x;
    if (t < 96){
        int b = t / 12, j = t % 12;
        const float* gi = g5 + b*256;
        if (j < 9){
            const float* w = fc3w + j*256;
            float a = fc3b[j];
            for (int c = 0; c < 256; c++) a = fmaf(gi[c], w[c], a);
            if (j == 0 || j == 4 || j == 8) a += 1.f;
            mat[b*9 + j] = a;
        } else {
            int d = j - 9;
            const float* w = fc4w + d*256;
            float a = fc4b[d];
            for (int c = 0; c < 256; c++) a = fmaf(gi[c], w[c], a);
            bias3[b*3 + d] = a;
        }
    }
}

// ---------------- final transform: out[b,d,n] ----------------
__global__ __launch_bounds__(256) void k_out(const float* __restrict__ x,
                                             const float* __restrict__ mat,
                                             const float* __restrict__ bias3,
                                             float* __restrict__ out)
{
    int i = blockIdx.x*256 + threadIdx.x;       // 0..98303
    int n = i & 4095, bd = i >> 12;
    int b = bd / 3, d = bd - b*3;
    const float* xb = x + (size_t)b*6*4096 + n;
    const float* M = mat + b*9;
    out[i] = xb[0]*M[d] + xb[4096]*M[3 + d] + xb[2*4096]*M[6 + d] + bias3[b*3 + d];
}

// ---------------- launch ----------------
extern "C" void kernel_launch(void* const* d_in, const int* in_sizes, int n_in,
                              void* d_out, int out_size, void* d_ws, size_t ws_size,
                              hipStream_t stream)
{
    const float* x     = (const float*)d_in[0];
    const float* w1    = (const float*)d_in[1];
    const float* bn1g  = (const float*)d_in[2];
    const float* bn1b  = (const float*)d_in[3];
    const float* w2    = (const float*)d_in[4];
    const float* bn2g  = (const float*)d_in[5];
    const float* bn2b  = (const float*)d_in[6];
    const float* w3    = (const float*)d_in[7];
    const float* bn3gm = (const float*)d_in[8];
    const float* bn3bt = (const float*)d_in[9];
    const float* fc1w  = (const float*)d_in[10];
    const float* bn4g  = (const float*)d_in[11];
    const float* bn4b  = (const float*)d_in[12];
    const float* fc2w  = (const float*)d_in[13];
    const float* bn5g  = (const float*)d_in[14];
    const float* bn5b  = (const float*)d_in[15];
    const float* fc3w  = (const float*)d_in[16];
    const float* fc3b  = (const float*)d_in[17];
    const float* fc4w  = (const float*)d_in[18];
    const float* fc4b  = (const float*)d_in[19];
    float* out = (float*)d_out;

    char* ws = (char*)d_ws;
    float* xtp   = (float*)(ws);
    float* w3t_g = (float*)(ws);                 // overwrites xtp AFTER k_conv12
    int*   idxb  = (int*)  (ws + 1048576);
    float* h2max = (float*)(ws + 3670016);
    float* zs    = (float*)(ws + 20447232);
    float* bn1sum = zs;            float* bn1sq = zs + 64;
    float* bn2sum = zs + 128;      float* bn2sq = zs + 256;
    float* bn3sum = zs + 384;      float* bn3sq = zs + 1408;
    unsigned int* gkey = (unsigned int*)(zs + 2432);
    float* tail  = (float*)(ws + 20489728);
    float* g     = tail;           // 8192
    float* h4    = tail + 8192;    // 4096
    float* g4    = tail + 12288;   // 4096
    float* h5    = tail + 16384;   // 2048
    float* g5    = tail + 18432;   // 2048
    float* mat   = tail + 20480;   // 72
    float* bias3 = tail + 20552;   // 24
    float* w2t_g = (float*)(ws + 20573568);      // 32KB

    hipMemsetAsync(zs, 0, 42496, stream);

    k_prep    <<<128,   256, 0, stream>>>(x, xtp, w2, w2t_g);
    k_topk    <<<4096,  256, 0, stream>>>(xtp, idxb);
    k_bn1stats<<<2048,  256, 0, stream>>>(xtp, idxb, w1, bn1sum, bn1sq);
    k_conv12  <<<8192,  256, 0, stream>>>(xtp, idxb, w1, w2t_g,
                                          bn1sum, bn1sq, bn1g, bn1b,
                                          h2max, bn2sum, bn2sq);
    k_wt3     <<<512,   256, 0, stream>>>(w3, w3t_g);
    k_conv3   <<<8192,  256, 0, stream>>>(h2max, bn2sum, bn2sq, bn2g, bn2b,
                                          w3t_g, bn3sum, bn3sq, gkey);
    k_bn3g    <<<4,     256, 0, stream>>>(bn3sum, bn3sq, gkey, bn3gm, bn3bt, g);
    k_fc      <<<1024,  256, 0, stream>>>(g, fc1w, h4, 1024, 512);
    k_bnb     <<<2,     256, 0, stream>>>(h4, bn4g, bn4b, g4, 512);
    k_fc      <<<512,   256, 0, stream>>>(g4, fc2w, h5, 512, 256);
    k_bnb     <<<1,     256, 0, stream>>>(h5, bn5g, bn5b, g5, 256);
    k_head    <<<1,     128, 0, stream>>>(g5, fc3w, fc3b, fc4w, fc4b, mat, bias3);
    k_out     <<<384,   256, 0, stream>>>(x, mat, bias3, out);
}

// Round 12
// 667.082 us; speedup vs baseline: 1.1828x; 1.0869x over previous
//
#include <hip/hip_runtime.h>
#include <math.h>
#include <stddef.h>

// TransformNet fused pipeline, fp32.
// B=8, C=6, N=4096, K=20.
//
// ws layout (bytes):
//   [0)          xtp   : 8*4096*8 floats (points padded to 8)    1,048,576
//                        (REUSED after k_conv12 as w3t: 128x1024 = 524,288)
//   [1048576)    idx   : 8*4096*20 ints                          2,621,440
//   [3670016)    h2max : 8*4096*128 floats                      16,777,216
//   [20447232)   zstats: zero-initialized stats block                42,496
//   [20489728)   tail  : g(8192) h4(4096) g4(4096)
//                        h5(2048) g5(2048) mat(72) bias3(24)        83,840
//   [20573568)   w2t_g : 64x128 floats (w2 transposed)              32,768

static constexpr float EPS_ = 1e-5f;

// ---------------- K1: transpose-pad points + squared norms (+ w2 transpose) ----------------
__global__ __launch_bounds__(256) void k_prep(const float* __restrict__ x,
                                              float* __restrict__ xtp,
                                              const float* __restrict__ w2,
                                              float* __restrict__ w2t)
{
    int i = blockIdx.x*256 + threadIdx.x;       // 0..32767  (b*4096+n)
    int b = i >> 12, n = i & 4095;
    const float* xb = x + (size_t)b*6*4096 + n;
    float v0 = xb[0], v1 = xb[4096], v2 = xb[2*4096];
    float v3 = xb[3*4096], v4 = xb[4*4096], v5 = xb[5*4096];
    float xx = v0*v0 + v1*v1 + v2*v2 + v3*v3 + v4*v4 + v5*v5;
    float4* o = (float4*)(xtp + (size_t)i*8);
    o[0] = make_float4(v0, v1, v2, v3);
    o[1] = make_float4(v4, v5, xx, 0.f);
    if (blockIdx.x < 2){                        // w2t[c][o] = w2[o][c]
        int e = blockIdx.x*256 + threadIdx.x;   // 0..511
        for (int q = e; q < 64*128; q += 512){
            int c = q >> 7, oo = q & 127;
            w2t[q] = w2[oo*64 + c];
        }
    }
}

// identical fmaf chain used in both the max pass and the recompute pass so
// values are bit-identical.
__device__ __forceinline__ float pd_calc(const float4 a0, const float4 a1,
                                         const float4 q0, const float4 q1)
{
    float dot = a0.x*q0.x;
    dot = fmaf(a0.y, q0.y, dot);
    dot = fmaf(a0.z, q0.z, dot);
    dot = fmaf(a0.w, q0.w, dot);
    dot = fmaf(a1.x, q1.x, dot);
    dot = fmaf(a1.y, q1.y, dot);
    return fmaf(2.f, dot, -a1.z - q1.z);
}

// monotone float<->uint key transform (order-preserving, exact)
__device__ __forceinline__ unsigned fkey_(float f){
    unsigned u = __float_as_uint(f);
    return (u & 0x80000000u) ? ~u : (u | 0x80000000u);
}
__device__ __forceinline__ float finv_(unsigned k){
    return (k & 0x80000000u) ? __uint_as_float(k & 0x7fffffffu)
                             : __uint_as_float(~k);
}

// ---------------- K2: top-20 (as a SET; downstream is order-invariant) ----------------
// 8 centers per block: the 32 q-point loads/thread amortize over 8 centers.
// Phases 3/4 run in two passes of 4 centers, reusing the candidate arrays.
#define TK_CAP 384
__global__ __launch_bounds__(256) void k_topk(const float* __restrict__ xtp,
                                              int* __restrict__ idxout)
{
    __shared__ float maxs[8][256];
    __shared__ float candv[4][TK_CAP];
    __shared__ int   candi[4][TK_CAP];
    __shared__ float Ts[8];
    __shared__ unsigned ccnt[4], ocnt[4], nwork;
    __shared__ unsigned short work[1024];

    const int t = threadIdx.x;
    const int rowbase = blockIdx.x << 3;        // 8 centers per block
    const int b = rowbase >> 12;
    const float* xb = xtp + ((size_t)b << 15);  // b*4096*8

    float4 c0[8], c1[8];
    #pragma unroll
    for (int c = 0; c < 8; c++){
        const float4* p = (const float4*)(xtp + (size_t)(rowbase + c)*8);
        c0[c] = p[0]; c1[c] = p[1];
    }

    // phase 1: per-thread max over its 16 points, all 8 centers
    float mx[8];
    #pragma unroll
    for (int c = 0; c < 8; c++) mx[c] = -INFINITY;
    {
        const float4* qp = (const float4*)(xb + (size_t)t*8);
        for (int i = 0; i < 16; i++){
            float4 q0 = qp[0], q1 = qp[1];
            #pragma unroll
            for (int c = 0; c < 8; c++)
                mx[c] = fmaxf(mx[c], pd_calc(c0[c], c1[c], q0, q1));
            qp += 512;                          // +256 points
        }
    }
    #pragma unroll
    for (int c = 0; c < 8; c++) maxs[c][t] = mx[c];
    __syncthreads();

    const int w = t >> 6, lane = t & 63;
    // phase 2: exact 20th-largest of maxima via ballot binary search (2/wave)
    for (int cc = w; cc < 8; cc += 4){
        unsigned k0 = fkey_(maxs[cc][lane]);
        unsigned k1 = fkey_(maxs[cc][64  + lane]);
        unsigned k2 = fkey_(maxs[cc][128 + lane]);
        unsigned k3 = fkey_(maxs[cc][192 + lane]);
        unsigned lo = 0u;
        for (int bit = 31; bit >= 0; bit--){
            unsigned cand = lo | (1u << bit);
            int cnt = __popcll(__ballot(k0 >= cand))
                    + __popcll(__ballot(k1 >= cand))
                    + __popcll(__ballot(k2 >= cand))
                    + __popcll(__ballot(k3 >= cand));
            if (cnt >= 20) lo = cand;
        }
        if (lane == 0) Ts[cc] = finv_(lo);
    }
    __syncthreads();

    for (int p = 0; p < 2; p++){
        const int cb = p << 2;                  // center base for this pass
        if (t < 4){ ccnt[t] = 0u; ocnt[t] = 0u; }
        if (t == 0) nwork = 0u;
        __syncthreads();

        // phase 3a: compact worklist of qualifying (center, src-thread)
        #pragma unroll
        for (int c = 0; c < 4; c++){
            if (mx[cb + c] >= Ts[cb + c]){
                unsigned pos = atomicAdd(&nwork, 1u);
                work[pos] = (unsigned short)((c << 8) | t);
            }
        }
        __syncthreads();

        // phase 3b: dense recompute; push candidates >= threshold
        {
            int total = (int)nwork << 4;
            for (int e = t; e < total; e += 256){
                int ct = work[e >> 4];
                int c = ct >> 8, src = ct & 255;
                int m = ((e & 15) << 8) | src;
                const float4* pp = (const float4*)(xb + (size_t)m*8);
                float4 q0 = pp[0], q1 = pp[1];
                float pd = pd_calc(c0[cb + c], c1[cb + c], q0, q1);
                if (pd >= Ts[cb + c]){
                    unsigned pos = atomicAdd(&ccnt[c], 1u);
                    if (pos < TK_CAP){ candv[c][pos] = pd; candi[c][pos] = m; }
                }
            }
        }
        __syncthreads();

        {   // phase 4: exact top-20 set of local center w
            int n = (int)min(ccnt[w], (unsigned)TK_CAP);
            unsigned key[6]; int id[6];
            #pragma unroll
            for (int j = 0; j < 6; j++){
                int pz = (j << 6) | lane;
                bool ok = pz < n;
                key[j] = ok ? fkey_(candv[w][pz]) : 0u; // 0 < any finite key
                id[j]  = ok ? candi[w][pz] : 0x7fffffff;
            }
            unsigned C = 0u;                            // cutoff key (20th largest)
            for (int bit = 31; bit >= 0; bit--){
                unsigned cand = C | (1u << bit);
                int cnt = 0;
                #pragma unroll
                for (int j = 0; j < 6; j++)
                    cnt += __popcll(__ballot(key[j] >= cand));
                if (cnt >= 20) C = cand;
            }
            int m = 0, e = 0;
            #pragma unroll
            for (int j = 0; j < 6; j++){
                m += __popcll(__ballot(key[j] > C));
                e += __popcll(__ballot(key[j] == C));
            }
            int* outp = idxout + (size_t)(rowbase + cb + w)*20;
            #pragma unroll
            for (int j = 0; j < 6; j++){
                if (key[j] > C){
                    unsigned pos = atomicAdd(&ocnt[w], 1u);
                    outp[pos] = id[j];
                }
            }
            int need = 20 - m;                          // >= 1; e >= need always
            if (e <= need){                             // no boundary tie surplus
                #pragma unroll
                for (int j = 0; j < 6; j++){
                    if (key[j] == C){
                        unsigned pos = atomicAdd(&ocnt[w], 1u);
                        outp[pos] = id[j];
                    }
                }
            } else {                                    // rare: ties at cutoff
                for (int r = 0; r < need; r++){
                    int loc = 0x7fffffff;
                    #pragma unroll
                    for (int j = 0; j < 6; j++)
                        if (key[j] == C && id[j] < loc) loc = id[j];
                    int g = loc;
                    #pragma unroll
                    for (int s = 1; s < 64; s <<= 1) g = min(g, __shfl_xor(g, s));
                    #pragma unroll
                    for (int j = 0; j < 6; j++){
                        if (key[j] == C && id[j] == g){
                            key[j] = 0u;               // remove; emit once
                            unsigned pos = atomicAdd(&ocnt[w], 1u);
                            outp[pos] = g;
                        }
                    }
                }
            }
        }
        __syncthreads();                        // protect candv/ccnt before reset
    }
}

// ---------------- K3: bn1 stats ----------------
__global__ __launch_bounds__(256) void k_bn1stats(const float* __restrict__ xtp,
                                                  const int* __restrict__ idxb,
                                                  const float* __restrict__ w1,
                                                  float* __restrict__ bn1sum,
                                                  float* __restrict__ bn1sq)
{
    __shared__ float fT[320*12];                // 16 rows * 20 nbrs * 12
    __shared__ float red[2][4][64];
    const int t = threadIdx.x;
    const int rowbase = blockIdx.x << 4;        // 16 rows
    const int b = rowbase >> 12;

    for (int s = t; s < 320; s += 256){
        int r = s / 20, k = s % 20;
        int grow = rowbase + r;
        int m = idxb[(size_t)grow*20 + k];
        const float4* pn = (const float4*)(xtp + (size_t)((b << 12) | m)*8);
        const float4* pc = (const float4*)(xtp + (size_t)grow*8);
        float4 n0 = pn[0], n1 = pn[1], c0 = pc[0], c1 = pc[1];
        float* f = fT + s*12;
        ((float4*)f)[0] = make_float4(n0.x-c0.x, n0.y-c0.y, n0.z-c0.z, n0.w-c0.w);
        ((float4*)f)[1] = make_float4(n1.x-c1.x, n1.y-c1.y, c0.x, c0.y);
        ((float4*)f)[2] = make_float4(c0.z, c0.w, c1.x, c1.y);
    }
    __syncthreads();
    const int o = t & 63, grp = t >> 6;
    float w[12];
    #pragma unroll
    for (int c = 0; c < 12; c++) w[c] = w1[o*12 + c];
    float sm = 0.f, sq = 0.f;
    for (int s = grp*80; s < grp*80 + 80; s++){
        const float* f = fT + s*12;
        float4 f0 = *(const float4*)(f);
        float4 fa = *(const float4*)(f + 4);
        float4 fb = *(const float4*)(f + 8);
        float h = w[0]*f0.x + w[1]*f0.y + w[2]*f0.z + w[3]*f0.w
                + w[4]*fa.x + w[5]*fa.y + w[6]*fa.z + w[7]*fa.w
                + w[8]*fb.x + w[9]*fb.y + w[10]*fb.z + w[11]*fb.w;
        sm += h; sq = fmaf(h, h, sq);
    }
    red[0][grp][o] = sm; red[1][grp][o] = sq;
    __syncthreads();
    if (t < 64){
        float a = red[0][0][t] + red[0][1][t] + red[0][2][t] + red[0][3][t];
        float c2 = red[1][0][t] + red[1][1][t] + red[1][2][t] + red[1][3][t];
        atomicAdd(bn1sum + t, a);
        atomicAdd(bn1sq + t, c2);
    }
}

// ---------------- K4: fused conv1+bn1+lrelu+conv2 -> max_k + bn2 stats ----------------
// 8 rows/block, 4096 blocks: per-thread tile 10 vec x 8 o (reads/FMA -31% vs
// 5x8 — LDS pipe is the binding resource). bn1 finalize inlined. f1s
// XOR-swizzled; w2 panels at 516-word stride. LDS 74KB -> 2 blocks/CU.
__global__ __launch_bounds__(256, 2) void k_conv12(
    const float* __restrict__ xtp, const int* __restrict__ idxb,
    const float* __restrict__ w1, const float* __restrict__ w2t,
    const float* __restrict__ bn1sum, const float* __restrict__ bn1sq,
    const float* __restrict__ bn1g, const float* __restrict__ bn1b,
    float* __restrict__ h2max, float* __restrict__ bn2sum, float* __restrict__ bn2sq)
{
    __shared__ float f1s[160*64];       // 40960 B  conv1 out, XOR-swizzled j
    __shared__ float w2u[16*516];       // 33024 B  w2 panels; fT alias; scratch alias
    const int t = threadIdx.x;
    const int rowbase = blockIdx.x << 3;
    const int b = rowbase >> 12;

    // w1 row + inline bn1 finalize (identical formula to the old k_bnfin)
    const int jch = t & 63;
    float wr[12];
    #pragma unroll
    for (int c = 0; c < 12; c++) wr[c] = w1[jch*12 + c];
    float s1, t1;
    {
        float mean = bn1sum[jch]*(1.f/655360.f);
        float var  = bn1sq[jch]*(1.f/655360.f) - mean*mean;
        s1 = bn1g[jch]/sqrtf(var + EPS_);
        t1 = bn1b[jch] - mean*s1;
    }

    float* fT = w2u;                    // fT[160][12] aliases first 1920 floats
    if (t < 160){
        int r = t / 20;
        int grow = rowbase + r;
        int m = idxb[(size_t)grow*20 + (t - r*20)];
        const float4* pn = (const float4*)(xtp + (size_t)((b << 12) | m)*8);
        const float4* pc = (const float4*)(xtp + (size_t)grow*8);
        float4 n0 = pn[0], n1 = pn[1], c0 = pc[0], c1 = pc[1];
        float* f = fT + t*12;
        ((float4*)f)[0] = make_float4(n0.x-c0.x, n0.y-c0.y, n0.z-c0.z, n0.w-c0.w);
        ((float4*)f)[1] = make_float4(n1.x-c1.x, n1.y-c1.y, c0.x, c0.y);
        ((float4*)f)[2] = make_float4(c0.z, c0.w, c1.x, c1.y);
    }
    __syncthreads();                    // sync1: fT ready
    {   // conv1 + bn1 + lrelu -> f1s (XOR-swizzled j within each vec row)
        for (int vid = t; vid < 10240; vid += 256){
            int vec = vid >> 6;
            const float* f = fT + vec*12;
            float4 f0 = *(const float4*)(f);
            float4 fa = *(const float4*)(f + 4);
            float4 fb = *(const float4*)(f + 8);
            float acc = wr[0]*f0.x + wr[1]*f0.y + wr[2]*f0.z + wr[3]*f0.w
                      + wr[4]*fa.x + wr[5]*fa.y + wr[6]*fa.z + wr[7]*fa.w
                      + wr[8]*fb.x + wr[9]*fb.y + wr[10]*fb.z + wr[11]*fb.w;
            float v = fmaf(s1, acc, t1);
            f1s[(vec << 6) + (jch ^ ((vec & 7) << 2))] = fmaxf(v, 0.2f*v);
        }
    }
    __syncthreads();                    // sync2: f1s ready, fT dead
    {   // short-liveness copy w2t -> w2u panels (linear coalesced global read)
        float4 tmp[8];
        #pragma unroll
        for (int i = 0; i < 8; i++) tmp[i] = ((const float4*)w2t)[t + (i << 8)];
        #pragma unroll
        for (int i = 0; i < 8; i++){
            int q = t + (i << 8);               // float4 id
            int jr = q >> 5, o4 = q & 31;
            *(float4*)&w2u[(o4 >> 1)*516 + (jr << 3) + ((o4 & 1) << 2)] = tmp[i];
        }
    }
    __syncthreads();                    // sync3: w2u ready

    // conv2: vg owns 10 vecs (= half of row vg>>1); og owns 8 o's
    const int vg = t & 15, og = t >> 4;
    const float* fp = f1s + vg*10*64;
    const float* wp = w2u + og*516;
    int xw[10];
    #pragma unroll
    for (int i = 0; i < 10; i++) xw[i] = ((vg*10 + i) & 7) << 2;

    float h[10][8];
    #pragma unroll
    for (int i = 0; i < 10; i++)
        #pragma unroll
        for (int oi = 0; oi < 8; oi++) h[i][oi] = 0.f;

    for (int jl = 0; jl < 64; jl += 4){
        float wv[4][8];
        #pragma unroll
        for (int jj = 0; jj < 4; jj++){
            *(float4*)&wv[jj][0] = *(const float4*)&wp[((jl + jj) << 3)];
            *(float4*)&wv[jj][4] = *(const float4*)&wp[((jl + jj) << 3) + 4];
        }
        #pragma unroll
        for (int i = 0; i < 10; i++){
            float fv[4];
            *(float4*)fv = *(const float4*)&fp[(i << 6) + (jl ^ xw[i])];
            #pragma unroll
            for (int jj = 0; jj < 4; jj++)
                #pragma unroll
                for (int oi = 0; oi < 8; oi++)
                    h[i][oi] = fmaf(fv[jj], wv[jj][oi], h[i][oi]);
        }
    }

    // fold the 10 k's in-register
    float mxl[8], sml[8], sql[8];
    #pragma unroll
    for (int oi = 0; oi < 8; oi++){
        float v = h[0][oi];
        mxl[oi] = v; sml[oi] = v; sql[oi] = v*v;
    }
    #pragma unroll
    for (int i = 1; i < 10; i++)
        #pragma unroll
        for (int oi = 0; oi < 8; oi++){
            float v = h[i][oi];
            mxl[oi] = fmaxf(mxl[oi], v);
            sml[oi] += v;
            sql[oi] = fmaf(v, v, sql[oi]);
        }
    __syncthreads();                    // sync4: f1s+w2u reusable
    {   // scratch in w2u: [3 stats][16 vg][128 o]
        int base = (vg << 7) + (og << 3);
        *(float4*)&w2u[base]        = *(float4*)&mxl[0];
        *(float4*)&w2u[base + 4]    = *(float4*)&mxl[4];
        *(float4*)&w2u[2048 + base]     = *(float4*)&sml[0];
        *(float4*)&w2u[2048 + base + 4] = *(float4*)&sml[4];
        *(float4*)&w2u[4096 + base]     = *(float4*)&sql[0];
        *(float4*)&w2u[4096 + base + 4] = *(float4*)&sql[4];
    }
    __syncthreads();                    // sync5
    for (int it = t; it < 1024; it += 256){
        int r = it >> 7, o = it & 127;  // row r = halves 2r, 2r+1
        float m = fmaxf(w2u[((r << 1) << 7) + o],
                        w2u[(((r << 1) | 1) << 7) + o]);
        h2max[(size_t)(rowbase + r)*128 + o] = m;
    }
    if (t < 128){
        float s = 0.f, qq = 0.f;
        #pragma unroll
        for (int u = 0; u < 16; u++){
            s  += w2u[2048 + (u << 7) + t];
            qq += w2u[4096 + (u << 7) + t];
        }
        atomicAdd(bn2sum + t, s);
        atomicAdd(bn2sq + t, qq);
    }
}

// ---------------- w3 transpose into dead xtp region ----------------
__global__ __launch_bounds__(256) void k_wt3(const float* __restrict__ w3,
                                             float* __restrict__ w3t)
{
    int i = blockIdx.x*256 + threadIdx.x;       // 0..131071
    int j = i >> 10, o = i & 1023;
    w3t[i] = w3[(size_t)o*128 + j];             // w3t[j][o]
}

// ---------------- K5: bn2+lrelu+conv3 -> bn3 stats + max over n ----------------
// bn2 finalize inlined into LDS. 64 rows/block; 4r x 4o per-thread tile;
// XCD-per-batch block remap. LDS ~67.6KB -> 2/CU.
__global__ __launch_bounds__(256, 2) void k_conv3(const float* __restrict__ h2max,
    const float* __restrict__ bn2sum, const float* __restrict__ bn2sq,
    const float* __restrict__ bn2g, const float* __restrict__ bn2b,
    const float* __restrict__ w3t,
    float* __restrict__ bn3sum, float* __restrict__ bn3sq, unsigned int* __restrict__ gkey)
{
    __shared__ float f2[64*132];        // 33792 B (pad 132; also scratch)
    __shared__ float w3s[8192];         // 32768 B  [j=128][o=64] linear
    __shared__ float bn2stL[256];       //  1024 B  inline bn2 finalize
    const int t = threadIdx.x;
    // XCD-contiguous remap: bid&7 -> XCD; each XCD owns one batch
    const int bid = blockIdx.x;                 // 0..8191
    const int idx = bid >> 3;                   // 0..1023
    const int rt = (bid & 7)*64 + (idx >> 4);   // 512 row tiles of 64
    const int ot = idx & 15;                    // 16 o-tiles of 64
    const int rowbase = rt << 6;
    const int obase = ot << 6;
    const int b = rowbase >> 12;

    if (t < 128){                       // identical formula to old k_bnfin
        float mean = bn2sum[t]*(1.f/655360.f);
        float var  = bn2sq[t]*(1.f/655360.f) - mean*mean;
        float s = bn2g[t]/sqrtf(var + EPS_);
        bn2stL[t] = s;
        bn2stL[128 + t] = bn2b[t] - mean*s;
    }
    __syncthreads();                    // bn2stL ready

    for (int e = t; e < 64*128; e += 256){
        int r = e >> 7, c = e & 127;
        float v = h2max[(size_t)(rowbase + r)*128 + c];
        float u = fmaf(bn2stL[c], v, bn2stL[128 + c]);
        f2[r*132 + c] = fmaxf(u, 0.2f*u);
    }
    {   // short-liveness copy of w3 panel -> w3s
        float4 tmp[8];
        #pragma unroll
        for (int i = 0; i < 8; i++){
            int q = t + (i << 8);               // 0..2047
            tmp[i] = *(const float4*)&w3t[(size_t)(q >> 4)*1024 + obase + ((q & 15) << 2)];
        }
        #pragma unroll
        for (int i = 0; i < 8; i++) ((float4*)w3s)[t + (i << 8)] = tmp[i];
    }
    __syncthreads();                    // sync1: f2 + w3s ready

    const int oq = t & 15, rg = t >> 4;
    const int o0 = oq << 2, r0 = rg << 2;       // 4 rows, 4 o per thread
    float h[4][4];
    #pragma unroll
    for (int rr = 0; rr < 4; rr++)
        #pragma unroll
        for (int oi = 0; oi < 4; oi++) h[rr][oi] = 0.f;

    for (int jl = 0; jl < 128; jl += 4){
        float wv[4][4];
        #pragma unroll
        for (int jj = 0; jj < 4; jj++)
            *(float4*)wv[jj] = *(const float4*)&w3s[(jl + jj)*64 + o0];
        float fr[4][4];
        #pragma unroll
        for (int rr = 0; rr < 4; rr++)
            *(float4*)fr[rr] = *(const float4*)&f2[(r0 + rr)*132 + jl];
        #pragma unroll
        for (int jj = 0; jj < 4; jj++)
            #pragma unroll
            for (int rr = 0; rr < 4; rr++)
                #pragma unroll
                for (int oi = 0; oi < 4; oi++)
                    h[rr][oi] = fmaf(fr[rr][jj], wv[jj][oi], h[rr][oi]);
    }

    // fold 4 rows in-register
    float sml[4], sql[4], mxl[4];
    #pragma unroll
    for (int oi = 0; oi < 4; oi++){
        float v = h[0][oi];
        sml[oi] = v; sql[oi] = v*v; mxl[oi] = v;
    }
    #pragma unroll
    for (int rr = 1; rr < 4; rr++)
        #pragma unroll
        for (int oi = 0; oi < 4; oi++){
            float v = h[rr][oi];
            sml[oi] += v;
            sql[oi] = fmaf(v, v, sql[oi]);
            mxl[oi] = fmaxf(mxl[oi], v);
        }
    __syncthreads();                    // sync2: f2 reusable as scratch
    float* scr = f2;                    // [3][16 rg][64 o]
    *(float4*)&scr[(rg << 6) + o0]        = *(float4*)&sml[0];
    *(float4*)&scr[1024 + (rg << 6) + o0] = *(float4*)&sql[0];
    *(float4*)&scr[2048 + (rg << 6) + o0] = *(float4*)&mxl[0];
    __syncthreads();                    // sync3
    if (t < 192){
        int stat = t >> 6, o = t & 63;
        if (stat == 0){
            float s = 0.f;
            #pragma unroll
            for (int g2 = 0; g2 < 16; g2++) s += scr[(g2 << 6) + o];
            atomicAdd(bn3sum + obase + o, s);
        } else if (stat == 1){
            float s = 0.f;
            #pragma unroll
            for (int g2 = 0; g2 < 16; g2++) s += scr[1024 + (g2 << 6) + o];
            atomicAdd(bn3sq + obase + o, s);
        } else {
            float m = scr[2048 + o];
            #pragma unroll
            for (int g2 = 1; g2 < 16; g2++) m = fmaxf(m, scr[2048 + (g2 << 6) + o]);
            unsigned u = __float_as_uint(m);
            unsigned key = (u & 0x80000000u) ? ~u : (u | 0x80000000u);
            atomicMax(gkey + (b << 10) + obase + o, key);
        }
    }
}

// ---------------- K5f: finalize bn3 + g = lrelu(bn3(gmax)) ----------------
__global__ void k_bn3g(const float* __restrict__ sum, const float* __restrict__ sq,
                       const unsigned int* __restrict__ gkey,
                       const float* __restrict__ gamma, const float* __restrict__ beta,
                       float* __restrict__ g)
{
    int o = blockIdx.x*256 + threadIdx.x;
    if (o < 1024){
        float mean = sum[o]*(1.f/32768.f);
        float var  = sq[o]*(1.f/32768.f) - mean*mean;
        float s = gamma[o]/sqrtf(var + EPS_);
        float tt = beta[o] - mean*s;
        for (int b = 0; b < 8; b++){
            unsigned k = gkey[(b << 10) + o];
            unsigned u = (k & 0x80000000u) ? (k & 0x7fffffffu) : ~k;
            float v = __uint_as_float(u);
            float xv = fmaf(s, v, tt);
            g[(b << 10) + o] = fmaxf(xv, 0.2f*xv);
        }
    }
}

// ---------------- FC: one wave per output ----------------
__global__ __launch_bounds__(256) void k_fc(const float* __restrict__ in,
                                            const float* __restrict__ w,
                                            float* __restrict__ out, int Kdim, int Odim)
{
    int wid = (blockIdx.x*256 + threadIdx.x) >> 6;
    int lane = threadIdx.x & 63;
    int nout = 8*Odim;
    if (wid >= nout) return;
    int b = wid / Odim, o = wid - b*Odim;
    const float* gi = in + (size_t)b*Kdim;
    const float* wr = w + (size_t)o*Kdim;
    float acc = 0.f;
    for (int c = lane; c < Kdim; c += 64) acc = fmaf(gi[c], wr[c], acc);
    #pragma unroll
    for (int s = 32; s > 0; s >>= 1) acc += __shfl_xor(acc, s);
    if (lane == 0) out[(size_t)b*Odim + o] = acc;
}

// ---------------- batch-BN (over B=8) + lrelu ----------------
__global__ void k_bnb(const float* __restrict__ h, const float* __restrict__ gamma,
                      const float* __restrict__ beta, float* __restrict__ g, int C)
{
    int o = blockIdx.x*256 + threadIdx.x;
    if (o < C){
        float s = 0.f, q = 0.f;
        for (int b = 0; b < 8; b++){ float v = h[(size_t)b*C + o]; s += v; q = fmaf(v, v, q); }
        float mean = s*0.125f;
        float var  = q*0.125f - mean*mean;
        float sc = gamma[o]/sqrtf(var + EPS_);
        float tt = beta[o] - mean*sc;
        for (int b = 0; b < 8; b++){
            float xv = fmaf(sc, h[(size_t)b*C + o], tt);
            g[(size_t)b*C + o] = fmaxf(xv, 0.2f*xv);
        }
    }
}

// ---------------- head: fc3 (-> I + 3x3) and fc4 (-> bias) ----------------
__global__ void k_head(const float* __restrict__ g5,
                       const float* __restrict__ fc3w, const float* __restrict__ fc3b,
                       const float* __restrict__ fc4w, const float* __restrict__ fc4b,
                       float* __restrict__ mat, float* __restrict__ bias3)
{
    int t = threadIdx.x;
    if (t < 96){
        int b = t / 12, j = t % 12;
        const float* gi = g5 + b*256;
        if (j < 9){
            const float* w = fc3w + j*256;
            float a = fc3b[j];
            for (int c = 0; c < 256; c++) a = fmaf(gi[c], w[c], a);
            if (j == 0 || j == 4 || j == 8) a += 1.f;
            mat[b*9 + j] = a;
        } else {
            int d = j - 9;
            const float* w = fc4w + d*256;
            float a = fc4b[d];
            for (int c = 0; c < 256; c++) a = fmaf(gi[c], w[c], a);
            bias3[b*3 + d] = a;
        }
    }
}

// ---------------- final transform: out[b,d,n] ----------------
__global__ __launch_bounds__(256) void k_out(const float* __restrict__ x,
                                             const float* __restrict__ mat,
                                             const float* __restrict__ bias3,
                                             float* __restrict__ out)
{
    int i = blockIdx.x*256 + threadIdx.x;       // 0..98303
    int n = i & 4095, bd = i >> 12;
    int b = bd / 3, d = bd - b*3;
    const float* xb = x + (size_t)b*6*4096 + n;
    const float* M = mat + b*9;
    out[i] = xb[0]*M[d] + xb[4096]*M[3 + d] + xb[2*4096]*M[6 + d] + bias3[b*3 + d];
}

// ---------------- launch ----------------
extern "C" void kernel_launch(void* const* d_in, const int* in_sizes, int n_in,
                              void* d_out, int out_size, void* d_ws, size_t ws_size,
                              hipStream_t stream)
{
    const float* x     = (const float*)d_in[0];
    const float* w1    = (const float*)d_in[1];
    const float* bn1g  = (const float*)d_in[2];
    const float* bn1b  = (const float*)d_in[3];
    const float* w2    = (const float*)d_in[4];
    const float* bn2g  = (const float*)d_in[5];
    const float* bn2b  = (const float*)d_in[6];
    const float* w3    = (const float*)d_in[7];
    const float* bn3gm = (const float*)d_in[8];
    const float* bn3bt = (const float*)d_in[9];
    const float* fc1w  = (const float*)d_in[10];
    const float* bn4g  = (const float*)d_in[11];
    const float* bn4b  = (const float*)d_in[12];
    const float* fc2w  = (const float*)d_in[13];
    const float* bn5g  = (const float*)d_in[14];
    const float* bn5b  = (const float*)d_in[15];
    const float* fc3w  = (const float*)d_in[16];
    const float* fc3b  = (const float*)d_in[17];
    const float* fc4w  = (const float*)d_in[18];
    const float* fc4b  = (const float*)d_in[19];
    float* out = (float*)d_out;

    char* ws = (char*)d_ws;
    float* xtp   = (float*)(ws);
    float* w3t_g = (float*)(ws);                 // overwrites xtp AFTER k_conv12
    int*   idxb  = (int*)  (ws + 1048576);
    float* h2max = (float*)(ws + 3670016);
    float* zs    = (float*)(ws + 20447232);
    float* bn1sum = zs;            float* bn1sq = zs + 64;
    float* bn2sum = zs + 128;      float* bn2sq = zs + 256;
    float* bn3sum = zs + 384;      float* bn3sq = zs + 1408;
    unsigned int* gkey = (unsigned int*)(zs + 2432);
    float* tail  = (float*)(ws + 20489728);
    float* g     = tail;           // 8192
    float* h4    = tail + 8192;    // 4096
    float* g4    = tail + 12288;   // 4096
    float* h5    = tail + 16384;   // 2048
    float* g5    = tail + 18432;   // 2048
    float* mat   = tail + 20480;   // 72
    float* bias3 = tail + 20552;   // 24
    float* w2t_g = (float*)(ws + 20573568);      // 32KB

    hipMemsetAsync(zs, 0, 42496, stream);

    k_prep    <<<128,   256, 0, stream>>>(x, xtp, w2, w2t_g);
    k_topk    <<<4096,  256, 0, stream>>>(xtp, idxb);
    k_bn1stats<<<2048,  256, 0, stream>>>(xtp, idxb, w1, bn1sum, bn1sq);
    k_conv12  <<<4096,  256, 0, stream>>>(xtp, idxb, w1, w2t_g,
                                          bn1sum, bn1sq, bn1g, bn1b,
                                          h2max, bn2sum, bn2sq);
    k_wt3     <<<512,   256, 0, stream>>>(w3, w3t_g);
    k_conv3   <<<8192,  256, 0, stream>>>(h2max, bn2sum, bn2sq, bn2g, bn2b,
                                          w3t_g, bn3sum, bn3sq, gkey);
    k_bn3g    <<<4,     256, 0, stream>>>(bn3sum, bn3sq, gkey, bn3gm, bn3bt, g);
    k_fc      <<<1024,  256, 0, stream>>>(g, fc1w, h4, 1024, 512);
    k_bnb     <<<2,     256, 0, stream>>>(h4, bn4g, bn4b, g4, 512);
    k_fc      <<<512,   256, 0, stream>>>(g4, fc2w, h5, 512, 256);
    k_bnb     <<<1,     256, 0, stream>>>(h5, bn5g, bn5b, g5, 256);
    k_head    <<<1,     128, 0, stream>>>(g5, fc3w, fc3b, fc4w, fc4b, mat, bias3);
    k_out     <<<384,   256, 0, stream>>>(x, mat, bias3, out);
}

// Round 13
// 648.778 us; speedup vs baseline: 1.2162x; 1.0282x over previous
//
#include <hip/hip_runtime.h>
#include <math.h>
#include <stddef.h>

// TransformNet fused pipeline, fp32.
// B=8, C=6, N=4096, K=20.
//
// ws layout (bytes):
//   [0)          xtp   : 8*4096*8 floats (points padded to 8)    1,048,576
//                        (REUSED after k_conv12 as w3t: 128x1024 = 524,288)
//   [1048576)    idx   : 8*4096*20 ints                          2,621,440
//   [3670016)    h2max : 8*4096*128 floats                      16,777,216
//   [20447232)   zstats: zero-initialized stats block                42,496
//   [20489728)   tail  : g(8192) h4(4096) g4(4096)
//                        h5(2048) g5(2048) mat(72) bias3(24)        83,840
//   [20573568)   w2t_g : 64x128 floats (w2 transposed)              32,768

static constexpr float EPS_ = 1e-5f;

// ---------------- K1: transpose-pad points + squared norms (+ w2 transpose) ----------------
__global__ __launch_bounds__(256) void k_prep(const float* __restrict__ x,
                                              float* __restrict__ xtp,
                                              const float* __restrict__ w2,
                                              float* __restrict__ w2t)
{
    int i = blockIdx.x*256 + threadIdx.x;       // 0..32767  (b*4096+n)
    int b = i >> 12, n = i & 4095;
    const float* xb = x + (size_t)b*6*4096 + n;
    float v0 = xb[0], v1 = xb[4096], v2 = xb[2*4096];
    float v3 = xb[3*4096], v4 = xb[4*4096], v5 = xb[5*4096];
    float xx = v0*v0 + v1*v1 + v2*v2 + v3*v3 + v4*v4 + v5*v5;
    float4* o = (float4*)(xtp + (size_t)i*8);
    o[0] = make_float4(v0, v1, v2, v3);
    o[1] = make_float4(v4, v5, xx, 0.f);
    if (blockIdx.x < 2){                        // w2t[c][o] = w2[o][c]
        int e = blockIdx.x*256 + threadIdx.x;   // 0..511
        for (int q = e; q < 64*128; q += 512){
            int c = q >> 7, oo = q & 127;
            w2t[q] = w2[oo*64 + c];
        }
    }
}

// identical fmaf chain used in both the max pass and the recompute pass so
// values are bit-identical.
__device__ __forceinline__ float pd_calc(const float4 a0, const float4 a1,
                                         const float4 q0, const float4 q1)
{
    float dot = a0.x*q0.x;
    dot = fmaf(a0.y, q0.y, dot);
    dot = fmaf(a0.z, q0.z, dot);
    dot = fmaf(a0.w, q0.w, dot);
    dot = fmaf(a1.x, q1.x, dot);
    dot = fmaf(a1.y, q1.y, dot);
    return fmaf(2.f, dot, -a1.z - q1.z);
}

// monotone float<->uint key transform (order-preserving, exact)
__device__ __forceinline__ unsigned fkey_(float f){
    unsigned u = __float_as_uint(f);
    return (u & 0x80000000u) ? ~u : (u | 0x80000000u);
}
__device__ __forceinline__ float finv_(unsigned k){
    return (k & 0x80000000u) ? __uint_as_float(k & 0x7fffffffu)
                             : __uint_as_float(~k);
}

// ---------------- K2: top-20 (as a SET; downstream is order-invariant) ----------------
// 8 centers per block: the 32 q-point loads/thread amortize over 8 centers.
// Phases 3/4 run in two passes of 4 centers, reusing the candidate arrays.
#define TK_CAP 384
__global__ __launch_bounds__(256) void k_topk(const float* __restrict__ xtp,
                                              int* __restrict__ idxout)
{
    __shared__ float maxs[8][256];
    __shared__ float candv[4][TK_CAP];
    __shared__ int   candi[4][TK_CAP];
    __shared__ float Ts[8];
    __shared__ unsigned ccnt[4], ocnt[4], nwork;
    __shared__ unsigned short work[1024];

    const int t = threadIdx.x;
    const int rowbase = blockIdx.x << 3;        // 8 centers per block
    const int b = rowbase >> 12;
    const float* xb = xtp + ((size_t)b << 15);  // b*4096*8

    float4 c0[8], c1[8];
    #pragma unroll
    for (int c = 0; c < 8; c++){
        const float4* p = (const float4*)(xtp + (size_t)(rowbase + c)*8);
        c0[c] = p[0]; c1[c] = p[1];
    }

    // phase 1: per-thread max over its 16 points, all 8 centers
    float mx[8];
    #pragma unroll
    for (int c = 0; c < 8; c++) mx[c] = -INFINITY;
    {
        const float4* qp = (const float4*)(xb + (size_t)t*8);
        for (int i = 0; i < 16; i++){
            float4 q0 = qp[0], q1 = qp[1];
            #pragma unroll
            for (int c = 0; c < 8; c++)
                mx[c] = fmaxf(mx[c], pd_calc(c0[c], c1[c], q0, q1));
            qp += 512;                          // +256 points
        }
    }
    #pragma unroll
    for (int c = 0; c < 8; c++) maxs[c][t] = mx[c];
    __syncthreads();

    const int w = t >> 6, lane = t & 63;
    // phase 2: exact 20th-largest of maxima via ballot binary search (2/wave)
    for (int cc = w; cc < 8; cc += 4){
        unsigned k0 = fkey_(maxs[cc][lane]);
        unsigned k1 = fkey_(maxs[cc][64  + lane]);
        unsigned k2 = fkey_(maxs[cc][128 + lane]);
        unsigned k3 = fkey_(maxs[cc][192 + lane]);
        unsigned lo = 0u;
        for (int bit = 31; bit >= 0; bit--){
            unsigned cand = lo | (1u << bit);
            int cnt = __popcll(__ballot(k0 >= cand))
                    + __popcll(__ballot(k1 >= cand))
                    + __popcll(__ballot(k2 >= cand))
                    + __popcll(__ballot(k3 >= cand));
            if (cnt >= 20) lo = cand;
        }
        if (lane == 0) Ts[cc] = finv_(lo);
    }
    __syncthreads();

    for (int p = 0; p < 2; p++){
        const int cb = p << 2;                  // center base for this pass
        if (t < 4){ ccnt[t] = 0u; ocnt[t] = 0u; }
        if (t == 0) nwork = 0u;
        __syncthreads();

        // phase 3a: compact worklist of qualifying (center, src-thread)
        #pragma unroll
        for (int c = 0; c < 4; c++){
            if (mx[cb + c] >= Ts[cb + c]){
                unsigned pos = atomicAdd(&nwork, 1u);
                work[pos] = (unsigned short)((c << 8) | t);
            }
        }
        __syncthreads();

        // phase 3b: dense recompute; push candidates >= threshold
        {
            int total = (int)nwork << 4;
            for (int e = t; e < total; e += 256){
                int ct = work[e >> 4];
                int c = ct >> 8, src = ct & 255;
                int m = ((e & 15) << 8) | src;
                const float4* pp = (const float4*)(xb + (size_t)m*8);
                float4 q0 = pp[0], q1 = pp[1];
                float pd = pd_calc(c0[cb + c], c1[cb + c], q0, q1);
                if (pd >= Ts[cb + c]){
                    unsigned pos = atomicAdd(&ccnt[c], 1u);
                    if (pos < TK_CAP){ candv[c][pos] = pd; candi[c][pos] = m; }
                }
            }
        }
        __syncthreads();

        {   // phase 4: exact top-20 set of local center w
            int n = (int)min(ccnt[w], (unsigned)TK_CAP);
            unsigned key[6]; int id[6];
            #pragma unroll
            for (int j = 0; j < 6; j++){
                int pz = (j << 6) | lane;
                bool ok = pz < n;
                key[j] = ok ? fkey_(candv[w][pz]) : 0u; // 0 < any finite key
                id[j]  = ok ? candi[w][pz] : 0x7fffffff;
            }
            unsigned C = 0u;                            // cutoff key (20th largest)
            for (int bit = 31; bit >= 0; bit--){
                unsigned cand = C | (1u << bit);
                int cnt = 0;
                #pragma unroll
                for (int j = 0; j < 6; j++)
                    cnt += __popcll(__ballot(key[j] >= cand));
                if (cnt >= 20) C = cand;
            }
            int m = 0, e = 0;
            #pragma unroll
            for (int j = 0; j < 6; j++){
                m += __popcll(__ballot(key[j] > C));
                e += __popcll(__ballot(key[j] == C));
            }
            int* outp = idxout + (size_t)(rowbase + cb + w)*20;
            #pragma unroll
            for (int j = 0; j < 6; j++){
                if (key[j] > C){
                    unsigned pos = atomicAdd(&ocnt[w], 1u);
                    outp[pos] = id[j];
                }
            }
            int need = 20 - m;                          // >= 1; e >= need always
            if (e <= need){                             // no boundary tie surplus
                #pragma unroll
                for (int j = 0; j < 6; j++){
                    if (key[j] == C){
                        unsigned pos = atomicAdd(&ocnt[w], 1u);
                        outp[pos] = id[j];
                    }
                }
            } else {                                    // rare: ties at cutoff
                for (int r = 0; r < need; r++){
                    int loc = 0x7fffffff;
                    #pragma unroll
                    for (int j = 0; j < 6; j++)
                        if (key[j] == C && id[j] < loc) loc = id[j];
                    int g = loc;
                    #pragma unroll
                    for (int s = 1; s < 64; s <<= 1) g = min(g, __shfl_xor(g, s));
                    #pragma unroll
                    for (int j = 0; j < 6; j++){
                        if (key[j] == C && id[j] == g){
                            key[j] = 0u;               // remove; emit once
                            unsigned pos = atomicAdd(&ocnt[w], 1u);
                            outp[pos] = g;
                        }
                    }
                }
            }
        }
        __syncthreads();                        // protect candv/ccnt before reset
    }
}

// ---------------- K3: bn1 stats ----------------
__global__ __launch_bounds__(256) void k_bn1stats(const float* __restrict__ xtp,
                                                  const int* __restrict__ idxb,
                                                  const float* __restrict__ w1,
                                                  float* __restrict__ bn1sum,
                                                  float* __restrict__ bn1sq)
{
    __shared__ float fT[320*12];                // 16 rows * 20 nbrs * 12
    __shared__ float red[2][4][64];
    const int t = threadIdx.x;
    const int rowbase = blockIdx.x << 4;        // 16 rows
    const int b = rowbase >> 12;

    for (int s = t; s < 320; s += 256){
        int r = s / 20, k = s % 20;
        int grow = rowbase + r;
        int m = idxb[(size_t)grow*20 + k];
        const float4* pn = (const float4*)(xtp + (size_t)((b << 12) | m)*8);
        const float4* pc = (const float4*)(xtp + (size_t)grow*8);
        float4 n0 = pn[0], n1 = pn[1], c0 = pc[0], c1 = pc[1];
        float* f = fT + s*12;
        ((float4*)f)[0] = make_float4(n0.x-c0.x, n0.y-c0.y, n0.z-c0.z, n0.w-c0.w);
        ((float4*)f)[1] = make_float4(n1.x-c1.x, n1.y-c1.y, c0.x, c0.y);
        ((float4*)f)[2] = make_float4(c0.z, c0.w, c1.x, c1.y);
    }
    __syncthreads();
    const int o = t & 63, grp = t >> 6;
    float w[12];
    #pragma unroll
    for (int c = 0; c < 12; c++) w[c] = w1[o*12 + c];
    float sm = 0.f, sq = 0.f;
    for (int s = grp*80; s < grp*80 + 80; s++){
        const float* f = fT + s*12;
        float4 f0 = *(const float4*)(f);
        float4 fa = *(const float4*)(f + 4);
        float4 fb = *(const float4*)(f + 8);
        float h = w[0]*f0.x + w[1]*f0.y + w[2]*f0.z + w[3]*f0.w
                + w[4]*fa.x + w[5]*fa.y + w[6]*fa.z + w[7]*fa.w
                + w[8]*fb.x + w[9]*fb.y + w[10]*fb.z + w[11]*fb.w;
        sm += h; sq = fmaf(h, h, sq);
    }
    red[0][grp][o] = sm; red[1][grp][o] = sq;
    __syncthreads();
    if (t < 64){
        float a = red[0][0][t] + red[0][1][t] + red[0][2][t] + red[0][3][t];
        float c2 = red[1][0][t] + red[1][1][t] + red[1][2][t] + red[1][3][t];
        atomicAdd(bn1sum + t, a);
        atomicAdd(bn1sq + t, c2);
    }
}

// ---------------- K4: fused conv1+bn1+lrelu+conv2 -> max_k + bn2 stats ----------------
// 8 rows/block, 4096 blocks, 10 vec x 8 o tile. Nonlinear swizzle key
// ((vec>>2)^vec)&7 spreads the 16 vg lanes over 8 bank-quads (2-way = free;
// the old linear key gave only 4 -> 4-way on all fv reads). Epilogue scratch
// padded to 132/row (vg*132 = 4vg mod 32 -> 8 quads; old vg*128 was 16-way).
__global__ __launch_bounds__(256, 2) void k_conv12(
    const float* __restrict__ xtp, const int* __restrict__ idxb,
    const float* __restrict__ w1, const float* __restrict__ w2t,
    const float* __restrict__ bn1sum, const float* __restrict__ bn1sq,
    const float* __restrict__ bn1g, const float* __restrict__ bn1b,
    float* __restrict__ h2max, float* __restrict__ bn2sum, float* __restrict__ bn2sq)
{
    __shared__ float f1s[160*64];       // 40960 B  conv1 out, swizzled j
    __shared__ float w2u[16*516];       // 33024 B  w2 panels; fT alias; scratch alias
    const int t = threadIdx.x;
    const int rowbase = blockIdx.x << 3;
    const int b = rowbase >> 12;

    // w1 row + inline bn1 finalize (identical formula to the old k_bnfin)
    const int jch = t & 63;
    float wr[12];
    #pragma unroll
    for (int c = 0; c < 12; c++) wr[c] = w1[jch*12 + c];
    float s1, t1;
    {
        float mean = bn1sum[jch]*(1.f/655360.f);
        float var  = bn1sq[jch]*(1.f/655360.f) - mean*mean;
        s1 = bn1g[jch]/sqrtf(var + EPS_);
        t1 = bn1b[jch] - mean*s1;
    }

    float* fT = w2u;                    // fT[160][12] aliases first 1920 floats
    if (t < 160){
        int r = t / 20;
        int grow = rowbase + r;
        int m = idxb[(size_t)grow*20 + (t - r*20)];
        const float4* pn = (const float4*)(xtp + (size_t)((b << 12) | m)*8);
        const float4* pc = (const float4*)(xtp + (size_t)grow*8);
        float4 n0 = pn[0], n1 = pn[1], c0 = pc[0], c1 = pc[1];
        float* f = fT + t*12;
        ((float4*)f)[0] = make_float4(n0.x-c0.x, n0.y-c0.y, n0.z-c0.z, n0.w-c0.w);
        ((float4*)f)[1] = make_float4(n1.x-c1.x, n1.y-c1.y, c0.x, c0.y);
        ((float4*)f)[2] = make_float4(c0.z, c0.w, c1.x, c1.y);
    }
    __syncthreads();                    // sync1: fT ready
    {   // conv1 + bn1 + lrelu -> f1s (nonlinear-swizzled j within each vec row)
        for (int vid = t; vid < 10240; vid += 256){
            int vec = vid >> 6;
            const float* f = fT + vec*12;
            float4 f0 = *(const float4*)(f);
            float4 fa = *(const float4*)(f + 4);
            float4 fb = *(const float4*)(f + 8);
            float acc = wr[0]*f0.x + wr[1]*f0.y + wr[2]*f0.z + wr[3]*f0.w
                      + wr[4]*fa.x + wr[5]*fa.y + wr[6]*fa.z + wr[7]*fa.w
                      + wr[8]*fb.x + wr[9]*fb.y + wr[10]*fb.z + wr[11]*fb.w;
            float v = fmaf(s1, acc, t1);
            int key = (((vec >> 2) ^ vec) & 7) << 2;
            f1s[(vec << 6) + (jch ^ key)] = fmaxf(v, 0.2f*v);
        }
    }
    __syncthreads();                    // sync2: f1s ready, fT dead
    {   // short-liveness copy w2t -> w2u panels (linear coalesced global read)
        float4 tmp[8];
        #pragma unroll
        for (int i = 0; i < 8; i++) tmp[i] = ((const float4*)w2t)[t + (i << 8)];
        #pragma unroll
        for (int i = 0; i < 8; i++){
            int q = t + (i << 8);               // float4 id
            int jr = q >> 5, o4 = q & 31;
            *(float4*)&w2u[(o4 >> 1)*516 + (jr << 3) + ((o4 & 1) << 2)] = tmp[i];
        }
    }
    __syncthreads();                    // sync3: w2u ready

    // conv2: vg owns 10 vecs (= half of row vg>>1); og owns 8 o's
    const int vg = t & 15, og = t >> 4;
    const float* fp = f1s + vg*10*64;
    const float* wp = w2u + og*516;
    int kw[10];
    #pragma unroll
    for (int i = 0; i < 10; i++){
        int vec = vg*10 + i;
        kw[i] = (((vec >> 2) ^ vec) & 7) << 2;
    }

    float h[10][8];
    #pragma unroll
    for (int i = 0; i < 10; i++)
        #pragma unroll
        for (int oi = 0; oi < 8; oi++) h[i][oi] = 0.f;

    for (int jl = 0; jl < 64; jl += 4){
        float wv[4][8];
        #pragma unroll
        for (int jj = 0; jj < 4; jj++){
            *(float4*)&wv[jj][0] = *(const float4*)&wp[((jl + jj) << 3)];
            *(float4*)&wv[jj][4] = *(const float4*)&wp[((jl + jj) << 3) + 4];
        }
        #pragma unroll
        for (int i = 0; i < 10; i++){
            float fv[4];
            *(float4*)fv = *(const float4*)&fp[(i << 6) + (jl ^ kw[i])];
            #pragma unroll
            for (int jj = 0; jj < 4; jj++)
                #pragma unroll
                for (int oi = 0; oi < 8; oi++)
                    h[i][oi] = fmaf(fv[jj], wv[jj][oi], h[i][oi]);
        }
    }

    // fold the 10 k's in-register
    float mxl[8], sml[8], sql[8];
    #pragma unroll
    for (int oi = 0; oi < 8; oi++){
        float v = h[0][oi];
        mxl[oi] = v; sml[oi] = v; sql[oi] = v*v;
    }
    #pragma unroll
    for (int i = 1; i < 10; i++)
        #pragma unroll
        for (int oi = 0; oi < 8; oi++){
            float v = h[i][oi];
            mxl[oi] = fmaxf(mxl[oi], v);
            sml[oi] += v;
            sql[oi] = fmaf(v, v, sql[oi]);
        }
    __syncthreads();                    // sync4: f1s+w2u reusable
    {   // scratch in w2u: [3 stats][16 vg][132 o] (pad spreads banks)
        int base = vg*132 + (og << 3);
        *(float4*)&w2u[base]        = *(float4*)&mxl[0];
        *(float4*)&w2u[base + 4]    = *(float4*)&mxl[4];
        *(float4*)&w2u[2112 + base]     = *(float4*)&sml[0];
        *(float4*)&w2u[2112 + base + 4] = *(float4*)&sml[4];
        *(float4*)&w2u[4224 + base]     = *(float4*)&sql[0];
        *(float4*)&w2u[4224 + base + 4] = *(float4*)&sql[4];
    }
    __syncthreads();                    // sync5
    for (int it = t; it < 1024; it += 256){
        int r = it >> 7, o = it & 127;  // row r = halves 2r, 2r+1
        float m = fmaxf(w2u[(r << 1)*132 + o],
                        w2u[((r << 1) | 1)*132 + o]);
        h2max[(size_t)(rowbase + r)*128 + o] = m;
    }
    if (t < 128){
        float s = 0.f, qq = 0.f;
        #pragma unroll
        for (int u = 0; u < 16; u++){
            s  += w2u[2112 + u*132 + t];
            qq += w2u[4224 + u*132 + t];
        }
        atomicAdd(bn2sum + t, s);
        atomicAdd(bn2sq + t, qq);
    }
}

// ---------------- w3 transpose into dead xtp region ----------------
__global__ __launch_bounds__(256) void k_wt3(const float* __restrict__ w3,
                                             float* __restrict__ w3t)
{
    int i = blockIdx.x*256 + threadIdx.x;       // 0..131071
    int j = i >> 10, o = i & 1023;
    w3t[i] = w3[(size_t)o*128 + j];             // w3t[j][o]
}

// ---------------- K5: bn2+lrelu+conv3 -> bn3 stats + max over n ----------------
// bn2 finalize inlined into LDS. 64 rows/block; 4r x 4o per-thread tile;
// XCD-per-batch block remap. LDS ~67.6KB -> 2/CU.
__global__ __launch_bounds__(256, 2) void k_conv3(const float* __restrict__ h2max,
    const float* __restrict__ bn2sum, const float* __restrict__ bn2sq,
    const float* __restrict__ bn2g, const float* __restrict__ bn2b,
    const float* __restrict__ w3t,
    float* __restrict__ bn3sum, float* __restrict__ bn3sq, unsigned int* __restrict__ gkey)
{
    __shared__ float f2[64*132];        // 33792 B (pad 132; also scratch)
    __shared__ float w3s[8192];         // 32768 B  [j=128][o=64] linear
    __shared__ float bn2stL[256];       //  1024 B  inline bn2 finalize
    const int t = threadIdx.x;
    // XCD-contiguous remap: bid&7 -> XCD; each XCD owns one batch
    const int bid = blockIdx.x;                 // 0..8191
    const int idx = bid >> 3;                   // 0..1023
    const int rt = (bid & 7)*64 + (idx >> 4);   // 512 row tiles of 64
    const int ot = idx & 15;                    // 16 o-tiles of 64
    const int rowbase = rt << 6;
    const int obase = ot << 6;
    const int b = rowbase >> 12;

    if (t < 128){                       // identical formula to old k_bnfin
        float mean = bn2sum[t]*(1.f/655360.f);
        float var  = bn2sq[t]*(1.f/655360.f) - mean*mean;
        float s = bn2g[t]/sqrtf(var + EPS_);
        bn2stL[t] = s;
        bn2stL[128 + t] = bn2b[t] - mean*s;
    }
    __syncthreads();                    // bn2stL ready

    for (int e = t; e < 64*128; e += 256){
        int r = e >> 7, c = e & 127;
        float v = h2max[(size_t)(rowbase + r)*128 + c];
        float u = fmaf(bn2stL[c], v, bn2stL[128 + c]);
        f2[r*132 + c] = fmaxf(u, 0.2f*u);
    }
    {   // short-liveness copy of w3 panel -> w3s
        float4 tmp[8];
        #pragma unroll
        for (int i = 0; i < 8; i++){
            int q = t + (i << 8);               // 0..2047
            tmp[i] = *(const float4*)&w3t[(size_t)(q >> 4)*1024 + obase + ((q & 15) << 2)];
        }
        #pragma unroll
        for (int i = 0; i < 8; i++) ((float4*)w3s)[t + (i << 8)] = tmp[i];
    }
    __syncthreads();                    // sync1: f2 + w3s ready

    const int oq = t & 15, rg = t >> 4;
    const int o0 = oq << 2, r0 = rg << 2;       // 4 rows, 4 o per thread
    float h[4][4];
    #pragma unroll
    for (int rr = 0; rr < 4; rr++)
        #pragma unroll
        for (int oi = 0; oi < 4; oi++) h[rr][oi] = 0.f;

    for (int jl = 0; jl < 128; jl += 4){
        float wv[4][4];
        #pragma unroll
        for (int jj = 0; jj < 4; jj++)
            *(float4*)wv[jj] = *(const float4*)&w3s[(jl + jj)*64 + o0];
        float fr[4][4];
        #pragma unroll
        for (int rr = 0; rr < 4; rr++)
            *(float4*)fr[rr] = *(const float4*)&f2[(r0 + rr)*132 + jl];
        #pragma unroll
        for (int jj = 0; jj < 4; jj++)
            #pragma unroll
            for (int rr = 0; rr < 4; rr++)
                #pragma unroll
                for (int oi = 0; oi < 4; oi++)
                    h[rr][oi] = fmaf(fr[rr][jj], wv[jj][oi], h[rr][oi]);
    }

    // fold 4 rows in-register
    float sml[4], sql[4], mxl[4];
    #pragma unroll
    for (int oi = 0; oi < 4; oi++){
        float v = h[0][oi];
        sml[oi] = v; sql[oi] = v*v; mxl[oi] = v;
    }
    #pragma unroll
    for (int rr = 1; rr < 4; rr++)
        #pragma unroll
        for (int oi = 0; oi < 4; oi++){
            float v = h[rr][oi];
            sml[oi] += v;
            sql[oi] = fmaf(v, v, sql[oi]);
            mxl[oi] = fmaxf(mxl[oi], v);
        }
    __syncthreads();                    // sync2: f2 reusable as scratch
    float* scr = f2;                    // [3][16 rg][64 o]
    *(float4*)&scr[(rg << 6) + o0]        = *(float4*)&sml[0];
    *(float4*)&scr[1024 + (rg << 6) + o0] = *(float4*)&sql[0];
    *(float4*)&scr[2048 + (rg << 6) + o0] = *(float4*)&mxl[0];
    __syncthreads();                    // sync3
    if (t < 192){
        int stat = t >> 6, o = t & 63;
        if (stat == 0){
            float s = 0.f;
            #pragma unroll
            for (int g2 = 0; g2 < 16; g2++) s += scr[(g2 << 6) + o];
            atomicAdd(bn3sum + obase + o, s);
        } else if (stat == 1){
            float s = 0.f;
            #pragma unroll
            for (int g2 = 0; g2 < 16; g2++) s += scr[1024 + (g2 << 6) + o];
            atomicAdd(bn3sq + obase + o, s);
        } else {
            float m = scr[2048 + o];
            #pragma unroll
            for (int g2 = 1; g2 < 16; g2++) m = fmaxf(m, scr[2048 + (g2 << 6) + o]);
            unsigned u = __float_as_uint(m);
            unsigned key = (u & 0x80000000u) ? ~u : (u | 0x80000000u);
            atomicMax(gkey + (b << 10) + obase + o, key);
        }
    }
}

// ---------------- K5f: finalize bn3 + g = lrelu(bn3(gmax)) ----------------
__global__ void k_bn3g(const float* __restrict__ sum, const float* __restrict__ sq,
                       const unsigned int* __restrict__ gkey,
                       const float* __restrict__ gamma, const float* __restrict__ beta,
                       float* __restrict__ g)
{
    int o = blockIdx.x*256 + threadIdx.x;
    if (o < 1024){
        float mean = sum[o]*(1.f/32768.f);
        float var  = sq[o]*(1.f/32768.f) - mean*mean;
        float s = gamma[o]/sqrtf(var + EPS_);
        float tt = beta[o] - mean*s;
        for (int b = 0; b < 8; b++){
            unsigned k = gkey[(b << 10) + o];
            unsigned u = (k & 0x80000000u) ? (k & 0x7fffffffu) : ~k;
            float v = __uint_as_float(u);
            float xv = fmaf(s, v, tt);
            g[(b << 10) + o] = fmaxf(xv, 0.2f*xv);
        }
    }
}

// ---------------- FC: one wave per output ----------------
__global__ __launch_bounds__(256) void k_fc(const float* __restrict__ in,
                                            const float* __restrict__ w,
                                            float* __restrict__ out, int Kdim, int Odim)
{
    int wid = (blockIdx.x*256 + threadIdx.x) >> 6;
    int lane = threadIdx.x & 63;
    int nout = 8*Odim;
    if (wid >= nout) return;
    int b = wid / Odim, o = wid - b*Odim;
    const float* gi = in + (size_t)b*Kdim;
    const float* wr = w + (size_t)o*Kdim;
    float acc = 0.f;
    for (int c = lane; c < Kdim; c += 64) acc = fmaf(gi[c], wr[c], acc);
    #pragma unroll
    for (int s = 32; s > 0; s >>= 1) acc += __shfl_xor(acc, s);
    if (lane == 0) out[(size_t)b*Odim + o] = acc;
}

// ---------------- batch-BN (over B=8) + lrelu ----------------
__global__ void k_bnb(const float* __restrict__ h, const float* __restrict__ gamma,
                      const float* __restrict__ beta, float* __restrict__ g, int C)
{
    int o = blockIdx.x*256 + threadIdx.x;
    if (o < C){
        float s = 0.f, q = 0.f;
        for (int b = 0; b < 8; b++){ float v = h[(size_t)b*C + o]; s += v; q = fmaf(v, v, q); }
        float mean = s*0.125f;
        float var  = q*0.125f - mean*mean;
        float sc = gamma[o]/sqrtf(var + EPS_);
        float tt = beta[o] - mean*sc;
        for (int b = 0; b < 8; b++){
            float xv = fmaf(sc, h[(size_t)b*C + o], tt);
            g[(size_t)b*C + o] = fmaxf(xv, 0.2f*xv);
        }
    }
}

// ---------------- head: fc3 (-> I + 3x3) and fc4 (-> bias) ----------------
__global__ void k_head(const float* __restrict__ g5,
                       const float* __restrict__ fc3w, const float* __restrict__ fc3b,
                       const float* __restrict__ fc4w, const float* __restrict__ fc4b,
                       float* __restrict__ mat, float* __restrict__ bias3)
{
    int t = threadIdx.x;
    if (t < 96){
        int b = t / 12, j = t % 12;
        const float* gi = g5 + b*256;
        if (j < 9){
            const float* w = fc3w + j*256;
            float a = fc3b[j];
            for (int c = 0; c < 256; c++) a = fmaf(gi[c], w[c], a);
            if (j == 0 || j == 4 || j == 8) a += 1.f;
            mat[b*9 + j] = a;
        } else {
            int d = j - 9;
            const float* w = fc4w + d*256;
            float a = fc4b[d];
            for (int c = 0; c < 256; c++) a = fmaf(gi[c], w[c], a);
            bias3[b*3 + d] = a;
        }
    }
}

// ---------------- final transform: out[b,d,n] ----------------
__global__ __launch_bounds__(256) void k_out(const float* __restrict__ x,
                                             const float* __restrict__ mat,
                                             const float* __restrict__ bias3,
                                             float* __restrict__ out)
{
    int i = blockIdx.x*256 + threadIdx.x;       // 0..98303
    int n = i & 4095, bd = i >> 12;
    int b = bd / 3, d = bd - b*3;
    const float* xb = x + (size_t)b*6*4096 + n;
    const float* M = mat + b*9;
    out[i] = xb[0]*M[d] + xb[4096]*M[3 + d] + xb[2*4096]*M[6 + d] + bias3[b*3 + d];
}

// ---------------- launch ----------------
extern "C" void kernel_launch(void* const* d_in, const int* in_sizes, int n_in,
                              void* d_out, int out_size, void* d_ws, size_t ws_size,
                              hipStream_t stream)
{
    const float* x     = (const float*)d_in[0];
    const float* w1    = (const float*)d_in[1];
    const float* bn1g  = (const float*)d_in[2];
    const float* bn1b  = (const float*)d_in[3];
    const float* w2    = (const float*)d_in[4];
    const float* bn2g  = (const float*)d_in[5];
    const float* bn2b  = (const float*)d_in[6];
    const float* w3    = (const float*)d_in[7];
    const float* bn3gm = (const float*)d_in[8];
    const float* bn3bt = (const float*)d_in[9];
    const float* fc1w  = (const float*)d_in[10];
    const float* bn4g  = (const float*)d_in[11];
    const float* bn4b  = (const float*)d_in[12];
    const float* fc2w  = (const float*)d_in[13];
    const float* bn5g  = (const float*)d_in[14];
    const float* bn5b  = (const float*)d_in[15];
    const float* fc3w  = (const float*)d_in[16];
    const float* fc3b  = (const float*)d_in[17];
    const float* fc4w  = (const float*)d_in[18];
    const float* fc4b  = (const float*)d_in[19];
    float* out = (float*)d_out;

    char* ws = (char*)d_ws;
    float* xtp   = (float*)(ws);
    float* w3t_g = (float*)(ws);                 // overwrites xtp AFTER k_conv12
    int*   idxb  = (int*)  (ws + 1048576);
    float* h2max = (float*)(ws + 3670016);
    float* zs    = (float*)(ws + 20447232);
    float* bn1sum = zs;            float* bn1sq = zs + 64;
    float* bn2sum = zs + 128;      float* bn2sq = zs + 256;
    float* bn3sum = zs + 384;      float* bn3sq = zs + 1408;
    unsigned int* gkey = (unsigned int*)(zs + 2432);
    float* tail  = (float*)(ws + 20489728);
    float* g     = tail;           // 8192
    float* h4    = tail + 8192;    // 4096
    float* g4    = tail + 12288;   // 4096
    float* h5    = tail + 16384;   // 2048
    float* g5    = tail + 18432;   // 2048
    float* mat   = tail + 20480;   // 72
    float* bias3 = tail + 20552;   // 24
    float* w2t_g = (float*)(ws + 20573568);      // 32KB

    hipMemsetAsync(zs, 0, 42496, stream);

    k_prep    <<<128,   256, 0, stream>>>(x, xtp, w2, w2t_g);
    k_topk    <<<4096,  256, 0, stream>>>(xtp, idxb);
    k_bn1stats<<<2048,  256, 0, stream>>>(xtp, idxb, w1, bn1sum, bn1sq);
    k_conv12  <<<4096,  256, 0, stream>>>(xtp, idxb, w1, w2t_g,
                                          bn1sum, bn1sq, bn1g, bn1b,
                                          h2max, bn2sum, bn2sq);
    k_wt3     <<<512,   256, 0, stream>>>(w3, w3t_g);
    k_conv3   <<<8192,  256, 0, stream>>>(h2max, bn2sum, bn2sq, bn2g, bn2b,
                                          w3t_g, bn3sum, bn3sq, gkey);
    k_bn3g    <<<4,     256, 0, stream>>>(bn3sum, bn3sq, gkey, bn3gm, bn3bt, g);
    k_fc      <<<1024,  256, 0, stream>>>(g, fc1w, h4, 1024, 512);
    k_bnb     <<<2,     256, 0, stream>>>(h4, bn4g, bn4b, g4, 512);
    k_fc      <<<512,   256, 0, stream>>>(g4, fc2w, h5, 512, 256);
    k_bnb     <<<1,     256, 0, stream>>>(h5, bn5g, bn5b, g5, 256);
    k_head    <<<1,     128, 0, stream>>>(g5, fc3w, fc3b, fc4w, fc4b, mat, bias3);
    k_out     <<<384,   256, 0, stream>>>(x, mat, bias3, out);
}